// Round 1
// baseline (1336.619 us; speedup 1.0000x reference)
//
#include <hip/hip_runtime.h>
#include <hip/hip_bf16.h>
#include <stdint.h>

// Problem: B=2, T=2048, D=1024, H=16, hd=64.  out = ((softmax(rope(q)·rope(k)ᵀ/8))·v) @ Wout
// Plan: sniff dtype -> QKV GEMM (bf16 MFMA) + fused RoPE -> VALU flash attention -> out GEMM.

#define TSEQ   2048
#define NBATCH 2
#define NHEAD  16
#define HDIM   64
#define DMODEL 1024
#define BT     (NBATCH * TSEQ)   // 4096

typedef unsigned short u16;
typedef short bf16x8 __attribute__((ext_vector_type(8)));
typedef float f32x4  __attribute__((ext_vector_type(4)));

__device__ __forceinline__ u16 f2b(float f) {           // fp32 -> bf16 RNE
  uint32_t u = __float_as_uint(f);
  u += 0x7fffu + ((u >> 16) & 1u);
  return (u16)(u >> 16);
}
__device__ __forceinline__ uint32_t pk2(float a, float b) {
  return (uint32_t)f2b(a) | ((uint32_t)f2b(b) << 16);
}
__device__ __forceinline__ float lo16(uint32_t v) { return __uint_as_float(v << 16); }
__device__ __forceinline__ float hi16(uint32_t v) { return __uint_as_float(v & 0xffff0000u); }

__device__ __forceinline__ float4 fma4(float4 a, float4 b, float4 c) {
  return make_float4(fmaf(a.x,b.x,c.x), fmaf(a.y,b.y,c.y), fmaf(a.z,b.z,c.z), fmaf(a.w,b.w,c.w));
}
__device__ __forceinline__ float4 fma4s(float s, float4 b, float4 c) {
  return make_float4(fmaf(s,b.x,c.x), fmaf(s,b.y,c.y), fmaf(s,b.z,c.z), fmaf(s,b.w,c.w));
}
__device__ __forceinline__ float4 mul4(float4 a, float s) {
  return make_float4(a.x*s, a.y*s, a.z*s, a.w*s);
}

// ---------------------------------------------------------------- dtype sniff
// If input buffers are bf16, even ushorts are genuine bf16 ~N(0,1): |v| in [1e-3,100]
// with ~99.9% probability. If fp32, even ushorts are low mantissa bits -> ~7%.
__global__ void sniff_kernel(const u16* x, int* flag) {
  __shared__ int cnt;
  if (threadIdx.x == 0) cnt = 0;
  __syncthreads();
  int c = 0;
  for (int i = threadIdx.x; i < 4096; i += 256) {
    float a = fabsf(lo16((uint32_t)x[2*i] << 16 >> 16 << 16 >> 16 ? (uint32_t)x[2*i] : (uint32_t)x[2*i]));
    a = fabsf(__uint_as_float(((uint32_t)x[2*i]) << 16));
    if (a > 1e-3f && a < 100.f) c++;
  }
  atomicAdd(&cnt, c);
  __syncthreads();
  if (threadIdx.x == 0) *flag = (cnt > 2048) ? 1 : 0;
}

// ------------------------------------------------------- QKV GEMM + RoPE
// x(4096,1024) @ Wqkv(1024,3072) -> q,k,v each [B][H][T][64] bf16.
// 64x64 tile, 4 waves, each wave: 16 rows x 64 cols = 4 MFMAs per K-step of 32.
__global__ __launch_bounds__(256) void qkv_rope_kernel(
    const void* __restrict__ xv, const void* __restrict__ wv,
    const int* __restrict__ flag,
    u16* __restrict__ Q, u16* __restrict__ K, u16* __restrict__ V)
{
  __shared__ u16 As[64 * 40];   // [row][k], pad 32->40 to break bank stride
  __shared__ u16 Bs[64 * 40];   // [n][k] (transposed so frag loads are contiguous)
  const int isb = *flag;
  const int tid = threadIdx.x;
  const int n0 = blockIdx.x * 64;       // 0..3071
  const int m0 = blockIdx.y * 64;       // 0..4095
  const int w = tid >> 6, l = tid & 63, lr = l & 15, lq = l >> 4;
  const int ar = tid >> 2, ak = (tid & 3) << 3;   // A staging: row, k-seg of 8
  const int bk = tid >> 3, bn = (tid & 7) << 3;   // B staging: k, n-seg of 8

  f32x4 acc[4] = {};

  for (int k0 = 0; k0 < 1024; k0 += 32) {
    __syncthreads();
    if (isb) {
      const u16* xg = (const u16*)xv + (size_t)(m0 + ar) * 1024 + k0 + ak;
      *(uint4*)&As[ar * 40 + ak] = *(const uint4*)xg;
      const u16* wg = (const u16*)wv + (size_t)(k0 + bk) * 3072 + n0 + bn;
      uint4 wb = *(const uint4*)wg;
      u16 tmp[8]; *(uint4*)tmp = wb;
      #pragma unroll
      for (int i = 0; i < 8; i++) Bs[(bn + i) * 40 + bk] = tmp[i];
    } else {
      const float* xg = (const float*)xv + (size_t)(m0 + ar) * 1024 + k0 + ak;
      float4 a0 = *(const float4*)xg, a1 = *(const float4*)(xg + 4);
      uint4 pk; pk.x = pk2(a0.x,a0.y); pk.y = pk2(a0.z,a0.w);
      pk.z = pk2(a1.x,a1.y); pk.w = pk2(a1.z,a1.w);
      *(uint4*)&As[ar * 40 + ak] = pk;
      const float* wg = (const float*)wv + (size_t)(k0 + bk) * 3072 + n0 + bn;
      float4 b0 = *(const float4*)wg, b1 = *(const float4*)(wg + 4);
      float tmp[8] = {b0.x,b0.y,b0.z,b0.w,b1.x,b1.y,b1.z,b1.w};
      #pragma unroll
      for (int i = 0; i < 8; i++) Bs[(bn + i) * 40 + bk] = f2b(tmp[i]);
    }
    __syncthreads();
    bf16x8 af = *(const bf16x8*)&As[(w * 16 + lr) * 40 + lq * 8];
    #pragma unroll
    for (int nb = 0; nb < 4; nb++) {
      bf16x8 bf = *(const bf16x8*)&Bs[(nb * 16 + lr) * 40 + lq * 8];
      acc[nb] = __builtin_amdgcn_mfma_f32_16x16x32_bf16(af, bf, acc[nb], 0, 0, 0);
    }
  }

  // Epilogue: C/D layout col=lane&15, row=quad*4+reg. Tile (64 cols) sits inside
  // exactly one section (q/k/v) and one head (both 64-aligned) -> uniform branch.
  const int sec = n0 >> 10;              // 0=q 1=k 2=v
  const int h = (n0 >> 6) & 15;
  u16* dst = (sec == 0) ? Q : (sec == 1) ? K : V;
  #pragma unroll
  for (int nb = 0; nb < 4; nb++) {
    const int d = nb * 16 + lr;          // head-dim index 0..63
    #pragma unroll
    for (int r = 0; r < 4; r++) {
      const int row = m0 + w * 16 + lq * 4 + r;
      const int b = row >> 11, t = row & 2047;
      float val = acc[nb][r];
      float res;
      if (sec < 2) {
        // rope partner (col d^1) lives in lane^1
        float prt = __shfl_xor(val, 1, 64);
        float invf = __expf(-(float)(d & 31) * 0.2878231366242557f); // ln(1e4)/32
        float th = (float)t * invf;
        float sn, cs;
        sincosf(th, &sn, &cs);
        res = fmaf(val, cs, ((d & 1) ? prt : -prt) * sn);
        if (sec == 0) res *= 0.125f;     // fold 1/sqrt(hd) into q
      } else {
        res = val;
      }
      dst[(((size_t)b * 16 + h) * 2048 + t) * 64 + d] = f2b(res);
    }
  }
}

// ------------------------------------------------------- attention (VALU, online softmax)
// One block = one (b,h) x 256 q-rows. Each thread: 2 rows x 32 dims; the 2-lane
// group {l, l^32} completes each dot with one shfl_xor. K/V tiles (64x64 fp32) in LDS.
__global__ __launch_bounds__(256) void attn_kernel(
    const u16* __restrict__ Q, const u16* __restrict__ K,
    const u16* __restrict__ V, u16* __restrict__ ATT)
{
  __shared__ float Ks[64 * 64];
  __shared__ float Vs[64 * 64];
  const int tid = threadIdx.x;
  const int bh = blockIdx.x >> 3;
  const int qt0 = (blockIdx.x & 7) << 8;
  const int w = tid >> 6, l = tid & 63;
  const int gi = l & 31;              // pair id within wave
  const int sl = l >> 5;              // which 32-dim half
  const int r0 = qt0 + w * 64 + gi * 2;
  const size_t base = (size_t)bh * (2048 * 64);

  float4 q0[8], q1[8];
  {
    const u16* qp0 = Q + base + (size_t)r0 * 64 + sl * 32;
    const u16* qp1 = qp0 + 64;
    #pragma unroll
    for (int i = 0; i < 4; i++) {
      uint4 u = *(const uint4*)(qp0 + i * 8);
      q0[2*i+0] = make_float4(lo16(u.x), hi16(u.x), lo16(u.y), hi16(u.y));
      q0[2*i+1] = make_float4(lo16(u.z), hi16(u.z), lo16(u.w), hi16(u.w));
      uint4 v = *(const uint4*)(qp1 + i * 8);
      q1[2*i+0] = make_float4(lo16(v.x), hi16(v.x), lo16(v.y), hi16(v.y));
      q1[2*i+1] = make_float4(lo16(v.z), hi16(v.z), lo16(v.w), hi16(v.w));
    }
  }
  float4 o0[8], o1[8];
  #pragma unroll
  for (int i = 0; i < 8; i++) {
    o0[i] = make_float4(0.f,0.f,0.f,0.f);
    o1[i] = make_float4(0.f,0.f,0.f,0.f);
  }
  float m0r = -1e30f, m1r = -1e30f, l0r = 0.f, l1r = 0.f;

  for (int s0 = 0; s0 < 2048; s0 += 64) {
    __syncthreads();
    { // stage K/V tile, bf16 -> fp32
      const int kr = tid >> 2, dsg = (tid & 3) << 4;
      const u16* kg = K + base + (size_t)(s0 + kr) * 64 + dsg;
      const u16* vg = V + base + (size_t)(s0 + kr) * 64 + dsg;
      uint4 ka = *(const uint4*)kg, kb = *(const uint4*)(kg + 8);
      uint4 va = *(const uint4*)vg, vb = *(const uint4*)(vg + 8);
      float* kd = &Ks[kr * 64 + dsg];
      float* vd = &Vs[kr * 64 + dsg];
      *(float4*)(kd + 0)  = make_float4(lo16(ka.x), hi16(ka.x), lo16(ka.y), hi16(ka.y));
      *(float4*)(kd + 4)  = make_float4(lo16(ka.z), hi16(ka.z), lo16(ka.w), hi16(ka.w));
      *(float4*)(kd + 8)  = make_float4(lo16(kb.x), hi16(kb.x), lo16(kb.y), hi16(kb.y));
      *(float4*)(kd + 12) = make_float4(lo16(kb.z), hi16(kb.z), lo16(kb.w), hi16(kb.w));
      *(float4*)(vd + 0)  = make_float4(lo16(va.x), hi16(va.x), lo16(va.y), hi16(va.y));
      *(float4*)(vd + 4)  = make_float4(lo16(va.z), hi16(va.z), lo16(va.w), hi16(va.w));
      *(float4*)(vd + 8)  = make_float4(lo16(vb.x), hi16(vb.x), lo16(vb.y), hi16(vb.y));
      *(float4*)(vd + 12) = make_float4(lo16(vb.z), hi16(vb.z), lo16(vb.w), hi16(vb.w));
    }
    __syncthreads();
    #pragma unroll 1
    for (int c0 = 0; c0 < 64; c0 += 8) {
      float sc0[8], sc1[8];
      float cm0 = -1e30f, cm1 = -1e30f;
      #pragma unroll
      for (int j = 0; j < 8; j++) {
        const float4* kk = (const float4*)&Ks[(c0 + j) * 64 + sl * 32];
        float4 p0a = make_float4(0.f,0.f,0.f,0.f), p0b = p0a, p1a = p0a, p1b = p0a;
        #pragma unroll
        for (int d4 = 0; d4 < 8; d4 += 2) {
          float4 k0v = kk[d4], k1v = kk[d4 + 1];
          p0a = fma4(q0[d4], k0v, p0a);
          p0b = fma4(q0[d4 + 1], k1v, p0b);
          p1a = fma4(q1[d4], k0v, p1a);
          p1b = fma4(q1[d4 + 1], k1v, p1b);
        }
        float s0v = (p0a.x + p0a.y + p0a.z + p0a.w) + (p0b.x + p0b.y + p0b.z + p0b.w);
        float s1v = (p1a.x + p1a.y + p1a.z + p1a.w) + (p1b.x + p1b.y + p1b.z + p1b.w);
        s0v += __shfl_xor(s0v, 32, 64);
        s1v += __shfl_xor(s1v, 32, 64);
        sc0[j] = s0v; sc1[j] = s1v;
        cm0 = fmaxf(cm0, s0v); cm1 = fmaxf(cm1, s1v);
      }
      float mn0 = fmaxf(m0r, cm0), mn1 = fmaxf(m1r, cm1);
      float al0 = __expf(m0r - mn0), al1 = __expf(m1r - mn1);
      l0r *= al0; l1r *= al1;
      #pragma unroll
      for (int i = 0; i < 8; i++) { o0[i] = mul4(o0[i], al0); o1[i] = mul4(o1[i], al1); }
      #pragma unroll
      for (int j = 0; j < 8; j++) {
        float p0 = __expf(sc0[j] - mn0);
        float p1 = __expf(sc1[j] - mn1);
        l0r += p0; l1r += p1;
        const float4* vv = (const float4*)&Vs[(c0 + j) * 64 + sl * 32];
        #pragma unroll
        for (int d4 = 0; d4 < 8; d4++) {
          float4 vval = vv[d4];
          o0[d4] = fma4s(p0, vval, o0[d4]);
          o1[d4] = fma4s(p1, vval, o1[d4]);
        }
      }
      m0r = mn0; m1r = mn1;
    }
  }
  const float inv0 = 1.f / l0r, inv1 = 1.f / l1r;
  const int b = bh >> 4, h = bh & 15;
  u16* op0 = ATT + ((size_t)(b * 2048 + r0) * 1024) + h * 64 + sl * 32;
  u16* op1 = op0 + 1024;
  #pragma unroll
  for (int i = 0; i < 4; i++) {
    uint4 u;
    u.x = pk2(o0[2*i].x * inv0, o0[2*i].y * inv0);
    u.y = pk2(o0[2*i].z * inv0, o0[2*i].w * inv0);
    u.z = pk2(o0[2*i+1].x * inv0, o0[2*i+1].y * inv0);
    u.w = pk2(o0[2*i+1].z * inv0, o0[2*i+1].w * inv0);
    *(uint4*)(op0 + i * 8) = u;
    uint4 v;
    v.x = pk2(o1[2*i].x * inv1, o1[2*i].y * inv1);
    v.y = pk2(o1[2*i].z * inv1, o1[2*i].w * inv1);
    v.z = pk2(o1[2*i+1].x * inv1, o1[2*i+1].y * inv1);
    v.w = pk2(o1[2*i+1].z * inv1, o1[2*i+1].w * inv1);
    *(uint4*)(op1 + i * 8) = v;
  }
}

// ------------------------------------------------------- output projection
__global__ __launch_bounds__(256) void outproj_kernel(
    const u16* __restrict__ A, const void* __restrict__ wv,
    const int* __restrict__ flag, void* __restrict__ outv)
{
  __shared__ u16 As[64 * 40];
  __shared__ u16 Bs[64 * 40];
  const int isb = *flag;
  const int tid = threadIdx.x;
  const int n0 = blockIdx.x * 64;
  const int m0 = blockIdx.y * 64;
  const int w = tid >> 6, l = tid & 63, lr = l & 15, lq = l >> 4;
  const int ar = tid >> 2, ak = (tid & 3) << 3;
  const int bk = tid >> 3, bn = (tid & 7) << 3;

  f32x4 acc[4] = {};

  for (int k0 = 0; k0 < 1024; k0 += 32) {
    __syncthreads();
    *(uint4*)&As[ar * 40 + ak] =
        *(const uint4*)(A + (size_t)(m0 + ar) * 1024 + k0 + ak);
    if (isb) {
      const u16* wg = (const u16*)wv + (size_t)(k0 + bk) * 1024 + n0 + bn;
      uint4 wb = *(const uint4*)wg;
      u16 tmp[8]; *(uint4*)tmp = wb;
      #pragma unroll
      for (int i = 0; i < 8; i++) Bs[(bn + i) * 40 + bk] = tmp[i];
    } else {
      const float* wg = (const float*)wv + (size_t)(k0 + bk) * 1024 + n0 + bn;
      float4 b0 = *(const float4*)wg, b1 = *(const float4*)(wg + 4);
      float tmp[8] = {b0.x,b0.y,b0.z,b0.w,b1.x,b1.y,b1.z,b1.w};
      #pragma unroll
      for (int i = 0; i < 8; i++) Bs[(bn + i) * 40 + bk] = f2b(tmp[i]);
    }
    __syncthreads();
    bf16x8 af = *(const bf16x8*)&As[(w * 16 + lr) * 40 + lq * 8];
    #pragma unroll
    for (int nb = 0; nb < 4; nb++) {
      bf16x8 bf = *(const bf16x8*)&Bs[(nb * 16 + lr) * 40 + lq * 8];
      acc[nb] = __builtin_amdgcn_mfma_f32_16x16x32_bf16(af, bf, acc[nb], 0, 0, 0);
    }
  }
  #pragma unroll
  for (int nb = 0; nb < 4; nb++) {
    #pragma unroll
    for (int r = 0; r < 4; r++) {
      const int row = m0 + w * 16 + lq * 4 + r;
      const int col = n0 + nb * 16 + lr;
      float val = acc[nb][r];
      if (isb) ((u16*)outv)[(size_t)row * 1024 + col] = f2b(val);
      else     ((float*)outv)[(size_t)row * 1024 + col] = val;
    }
  }
}

extern "C" void kernel_launch(void* const* d_in, const int* in_sizes, int n_in,
                              void* d_out, int out_size, void* d_ws, size_t ws_size,
                              hipStream_t stream)
{
  const void* x    = d_in[0];
  const void* wqkv = d_in[1];
  const void* wout = d_in[2];
  char* ws = (char*)d_ws;
  int* flag = (int*)ws;
  u16* Q   = (u16*)(ws + 4096);
  u16* K   = Q + 4194304;     // 2*16*2048*64
  u16* V   = K + 4194304;
  u16* ATT = V + 4194304;     // total ws use: ~32 MB + 4 KB

  sniff_kernel<<<1, 256, 0, stream>>>((const u16*)x, flag);
  qkv_rope_kernel<<<dim3(48, 64), 256, 0, stream>>>(x, wqkv, flag, Q, K, V);
  attn_kernel<<<256, 256, 0, stream>>>(Q, K, V, ATT);
  outproj_kernel<<<dim3(16, 64), 256, 0, stream>>>(ATT, wout, flag, d_out);
}

// Round 2
// 388.659 us; speedup vs baseline: 3.4391x; 3.4391x over previous
//
#include <hip/hip_runtime.h>
#include <hip/hip_bf16.h>
#include <stdint.h>

// B=2, T=2048, D=1024, H=16, hd=64.  out = ((softmax(rope(q)·rope(k)ᵀ/8))·v) @ Wout
// R2: MFMA flash attention (no-max-sub softmax, exp2 with log2e folded into q,
//     V stored transposed [bh][d][t] for contiguous PV B-frag reads).

#define TSEQ   2048
#define NBATCH 2
#define NHEAD  16
#define HDIM   64
#define DMODEL 1024

typedef unsigned short u16;
typedef short bf16x8 __attribute__((ext_vector_type(8)));
typedef float f32x4  __attribute__((ext_vector_type(4)));

#if defined(__has_builtin) && __has_builtin(__builtin_amdgcn_exp2f)
#define EXP2F(x) __builtin_amdgcn_exp2f(x)
#else
#define EXP2F(x) exp2f(x)
#endif

__device__ __forceinline__ u16 f2b(float f) {           // fp32 -> bf16 RNE
  uint32_t u = __float_as_uint(f);
  u += 0x7fffu + ((u >> 16) & 1u);
  return (u16)(u >> 16);
}
__device__ __forceinline__ uint32_t pk2(float a, float b) {
  return (uint32_t)f2b(a) | ((uint32_t)f2b(b) << 16);
}
__device__ __forceinline__ float lo16(uint32_t v) { return __uint_as_float(v << 16); }

// ---------------------------------------------------------------- dtype sniff
// If input buffers are bf16, even ushorts are genuine bf16 ~N(0,1): |v| in [1e-3,100]
// with ~99.9% probability. If fp32, even ushorts are low mantissa bits -> ~7%.
__global__ void sniff_kernel(const u16* x, int* flag) {
  __shared__ int cnt;
  if (threadIdx.x == 0) cnt = 0;
  __syncthreads();
  int c = 0;
  for (int i = threadIdx.x; i < 4096; i += 256) {
    float a = fabsf(__uint_as_float(((uint32_t)x[2*i]) << 16));
    if (a > 1e-3f && a < 100.f) c++;
  }
  atomicAdd(&cnt, c);
  __syncthreads();
  if (threadIdx.x == 0) *flag = (cnt > 2048) ? 1 : 0;
}

// ------------------------------------------------------- QKV GEMM + RoPE
// x(4096,1024) @ Wqkv(1024,3072) -> Q,K [bh][t][64]; V transposed [bh][d][t].
// q gets 0.125 (1/sqrt(hd)) * log2(e) folded in so attention can use exp2.
__global__ __launch_bounds__(256) void qkv_rope_kernel(
    const void* __restrict__ xv, const void* __restrict__ wv,
    const int* __restrict__ flag,
    u16* __restrict__ Q, u16* __restrict__ K, u16* __restrict__ Vt)
{
  __shared__ u16 As[64 * 40];
  __shared__ u16 Bs[64 * 40];
  const int isb = *flag;
  const int tid = threadIdx.x;
  const int n0 = blockIdx.x * 64;       // 0..3071
  const int m0 = blockIdx.y * 64;       // 0..4095
  const int w = tid >> 6, l = tid & 63, lr = l & 15, lq = l >> 4;
  const int ar = tid >> 2, ak = (tid & 3) << 3;
  const int bk = tid >> 3, bn = (tid & 7) << 3;

  f32x4 acc[4] = {};

  for (int k0 = 0; k0 < 1024; k0 += 32) {
    __syncthreads();
    if (isb) {
      const u16* xg = (const u16*)xv + (size_t)(m0 + ar) * 1024 + k0 + ak;
      *(uint4*)&As[ar * 40 + ak] = *(const uint4*)xg;
      const u16* wg = (const u16*)wv + (size_t)(k0 + bk) * 3072 + n0 + bn;
      uint4 wb = *(const uint4*)wg;
      u16 tmp[8]; *(uint4*)tmp = wb;
      #pragma unroll
      for (int i = 0; i < 8; i++) Bs[(bn + i) * 40 + bk] = tmp[i];
    } else {
      const float* xg = (const float*)xv + (size_t)(m0 + ar) * 1024 + k0 + ak;
      float4 a0 = *(const float4*)xg, a1 = *(const float4*)(xg + 4);
      uint4 pk; pk.x = pk2(a0.x,a0.y); pk.y = pk2(a0.z,a0.w);
      pk.z = pk2(a1.x,a1.y); pk.w = pk2(a1.z,a1.w);
      *(uint4*)&As[ar * 40 + ak] = pk;
      const float* wg = (const float*)wv + (size_t)(k0 + bk) * 3072 + n0 + bn;
      float4 b0 = *(const float4*)wg, b1 = *(const float4*)(wg + 4);
      float tmp[8] = {b0.x,b0.y,b0.z,b0.w,b1.x,b1.y,b1.z,b1.w};
      #pragma unroll
      for (int i = 0; i < 8; i++) Bs[(bn + i) * 40 + bk] = f2b(tmp[i]);
    }
    __syncthreads();
    bf16x8 af = *(const bf16x8*)&As[(w * 16 + lr) * 40 + lq * 8];
    #pragma unroll
    for (int nb = 0; nb < 4; nb++) {
      bf16x8 bf = *(const bf16x8*)&Bs[(nb * 16 + lr) * 40 + lq * 8];
      acc[nb] = __builtin_amdgcn_mfma_f32_16x16x32_bf16(af, bf, acc[nb], 0, 0, 0);
    }
  }

  const int sec = n0 >> 10;              // 0=q 1=k 2=v
  const int h = (n0 >> 6) & 15;
  if (sec == 2) {
    // V transposed: Vt[((bh)*64 + d)*2048 + t], 4 consecutive t -> one 8B store
    #pragma unroll
    for (int nb = 0; nb < 4; nb++) {
      const int d = nb * 16 + lr;
      const int row0 = m0 + w * 16 + lq * 4;
      const int b = row0 >> 11, t0 = row0 & 2047;
      uint2 uv;
      uv.x = pk2(acc[nb][0], acc[nb][1]);
      uv.y = pk2(acc[nb][2], acc[nb][3]);
      *(uint2*)&Vt[(((size_t)b * 16 + h) * 64 + d) * 2048 + t0] = uv;
    }
  } else {
    u16* dst = (sec == 0) ? Q : K;
    const float qscale = 0.125f * 1.44269504f;  // 1/sqrt(hd) * log2(e)
    #pragma unroll
    for (int nb = 0; nb < 4; nb++) {
      const int d = nb * 16 + lr;
      #pragma unroll
      for (int r = 0; r < 4; r++) {
        const int row = m0 + w * 16 + lq * 4 + r;
        const int b = row >> 11, t = row & 2047;
        float val = acc[nb][r];
        // rope partner (col d^1) lives in lane^1
        float prt = __shfl_xor(val, 1, 64);
        float invf = __expf(-(float)(d & 31) * 0.2878231366242557f); // ln(1e4)/32
        float th = (float)t * invf;
        float sn, cs;
        sincosf(th, &sn, &cs);
        float res = fmaf(val, cs, ((d & 1) ? prt : -prt) * sn);
        if (sec == 0) res *= qscale;
        dst[(((size_t)b * 16 + h) * 2048 + t) * 64 + d] = f2b(res);
      }
    }
  }
}

// ------------------------------------------------------- MFMA flash attention
// Block = 2 waves, 128 q-rows of one (b,h). Wave owns 64 q-rows.
// KV-tile = 64. No max-subtraction: P = exp2(S_log2e), row-sum deferred.
__global__ __launch_bounds__(128, 2) void attn_kernel(
    const u16* __restrict__ Q, const u16* __restrict__ K,
    const u16* __restrict__ Vt, u16* __restrict__ ATT)
{
  __shared__ u16 Ks[64 * 72];       // [s][d] padded
  __shared__ u16 Vs[64 * 72];       // [d][s] padded (V^T tile)
  __shared__ u16 Ps[2 * 64 * 72];   // per-wave [m][s] padded
  const int tid = threadIdx.x;
  const int w = tid >> 6, l = tid & 63, lr = l & 15, lq = l >> 4;
  const int bh = blockIdx.x >> 4;
  const int qt = blockIdx.x & 15;
  const size_t base = (size_t)bh * (2048 * 64);
  const int qrow0 = qt * 128 + w * 64;
  u16* Psw = Ps + w * (64 * 72);

  // Q fragments (A-layout: m=lane&15, k=quad*8+j), held in registers
  bf16x8 qf[4][2];
  #pragma unroll
  for (int mb = 0; mb < 4; mb++)
    #pragma unroll
    for (int kc = 0; kc < 2; kc++)
      qf[mb][kc] = *(const bf16x8*)(Q + base + (size_t)(qrow0 + mb * 16 + lr) * 64 + kc * 32 + lq * 8);

  f32x4 oa[4][4] = {};    // [mb][nb=d-block], C/D layout
  f32x4 lsum[4] = {};     // per-lane partial row sums [mb][reg]

  const int sr = tid >> 1;            // staging row 0..63
  const int sc = (tid & 1) * 32;      // staging col segment

  #pragma unroll 1
  for (int s0 = 0; s0 < 2048; s0 += 64) {
    __syncthreads();
    {
      const u16* kg = K + base + (size_t)(s0 + sr) * 64 + sc;
      const u16* vg = Vt + base + (size_t)sr * 2048 + s0 + sc;
      #pragma unroll
      for (int i = 0; i < 4; i++) {
        *(uint4*)&Ks[sr * 72 + sc + i * 8] = *(const uint4*)(kg + i * 8);
        *(uint4*)&Vs[sr * 72 + sc + i * 8] = *(const uint4*)(vg + i * 8);
      }
    }
    __syncthreads();

    // ---- S = Q·K^T ; P = exp2(S) ; pack bf16 -> Ps (per-wave region)
    bf16x8 kf[4][2];
    #pragma unroll
    for (int nb = 0; nb < 4; nb++)
      #pragma unroll
      for (int kc = 0; kc < 2; kc++)
        kf[nb][kc] = *(const bf16x8*)&Ks[(nb * 16 + lr) * 72 + kc * 32 + lq * 8];

    const int ev = (lr & 1) == 0;
    #pragma unroll
    for (int mb = 0; mb < 4; mb++) {
      #pragma unroll
      for (int nb = 0; nb < 4; nb++) {
        f32x4 s = {};
        s = __builtin_amdgcn_mfma_f32_16x16x32_bf16(qf[mb][0], kf[nb][0], s, 0, 0, 0);
        s = __builtin_amdgcn_mfma_f32_16x16x32_bf16(qf[mb][1], kf[nb][1], s, 0, 0, 0);
        float e0 = EXP2F(s[0]), e1 = EXP2F(s[1]), e2 = EXP2F(s[2]), e3 = EXP2F(s[3]);
        lsum[mb][0] += e0; lsum[mb][1] += e1;
        lsum[mb][2] += e2; lsum[mb][3] += e3;
        // pack rows (quad*4+r, col=lr) -> col-pair u32 writes; even lanes write
        // rows r0,r0+1, odd lanes rows r0+2,r0+3 of their col-pair.
        uint32_t p01 = (uint32_t)f2b(e0) | ((uint32_t)f2b(e1) << 16);
        uint32_t p23 = (uint32_t)f2b(e2) | ((uint32_t)f2b(e3) << 16);
        uint32_t pp01 = (uint32_t)__shfl_xor((int)p01, 1, 64);
        uint32_t pp23 = (uint32_t)__shfl_xor((int)p23, 1, 64);
        uint32_t wA = ev ? ((p01 & 0xffffu) | (pp01 << 16))
                         : ((pp23 & 0xffffu) | (p23 << 16));
        uint32_t wB = ev ? ((p01 >> 16) | (pp01 & 0xffff0000u))
                         : ((pp23 >> 16) | (p23 & 0xffff0000u));
        const int row0 = mb * 16 + lq * 4 + (ev ? 0 : 2);
        const int c = nb * 16 + (lr & ~1);
        *(uint32_t*)&Psw[row0 * 72 + c] = wA;
        *(uint32_t*)&Psw[(row0 + 1) * 72 + c] = wB;
      }
    }

    // ---- O += P·V   (B-frag from Vs = V^T tile, contiguous)
    bf16x8 vf[4][2];
    #pragma unroll
    for (int nb = 0; nb < 4; nb++)
      #pragma unroll
      for (int kc = 0; kc < 2; kc++)
        vf[nb][kc] = *(const bf16x8*)&Vs[(nb * 16 + lr) * 72 + kc * 32 + lq * 8];

    #pragma unroll
    for (int mb = 0; mb < 4; mb++) {
      bf16x8 pf0 = *(const bf16x8*)&Psw[(mb * 16 + lr) * 72 + lq * 8];
      bf16x8 pf1 = *(const bf16x8*)&Psw[(mb * 16 + lr) * 72 + 32 + lq * 8];
      #pragma unroll
      for (int nb = 0; nb < 4; nb++) {
        oa[mb][nb] = __builtin_amdgcn_mfma_f32_16x16x32_bf16(pf0, vf[nb][0], oa[mb][nb], 0, 0, 0);
        oa[mb][nb] = __builtin_amdgcn_mfma_f32_16x16x32_bf16(pf1, vf[nb][1], oa[mb][nb], 0, 0, 0);
      }
    }
  }

  // ---- finalize: reduce row sums across the 16 lanes of each row group
  const int b = bh >> 4, h = bh & 15;
  #pragma unroll
  for (int mb = 0; mb < 4; mb++) {
    #pragma unroll
    for (int r = 0; r < 4; r++) {
      float v = lsum[mb][r];
      v += __shfl_xor(v, 1, 64);
      v += __shfl_xor(v, 2, 64);
      v += __shfl_xor(v, 4, 64);
      v += __shfl_xor(v, 8, 64);
      lsum[mb][r] = 1.f / v;
    }
    #pragma unroll
    for (int nb = 0; nb < 4; nb++) {
      const int d = nb * 16 + lr;
      #pragma unroll
      for (int r = 0; r < 4; r++) {
        const int t = qrow0 + mb * 16 + lq * 4 + r;
        ATT[((size_t)(b * 2048 + t)) * 1024 + h * 64 + d] = f2b(oa[mb][nb][r] * lsum[mb][r]);
      }
    }
  }
}

// ------------------------------------------------------- output projection
__global__ __launch_bounds__(256) void outproj_kernel(
    const u16* __restrict__ A, const void* __restrict__ wv,
    const int* __restrict__ flag, void* __restrict__ outv)
{
  __shared__ u16 As[64 * 40];
  __shared__ u16 Bs[64 * 40];
  const int isb = *flag;
  const int tid = threadIdx.x;
  const int n0 = blockIdx.x * 64;
  const int m0 = blockIdx.y * 64;
  const int w = tid >> 6, l = tid & 63, lr = l & 15, lq = l >> 4;
  const int ar = tid >> 2, ak = (tid & 3) << 3;
  const int bk = tid >> 3, bn = (tid & 7) << 3;

  f32x4 acc[4] = {};

  for (int k0 = 0; k0 < 1024; k0 += 32) {
    __syncthreads();
    *(uint4*)&As[ar * 40 + ak] =
        *(const uint4*)(A + (size_t)(m0 + ar) * 1024 + k0 + ak);
    if (isb) {
      const u16* wg = (const u16*)wv + (size_t)(k0 + bk) * 1024 + n0 + bn;
      uint4 wb = *(const uint4*)wg;
      u16 tmp[8]; *(uint4*)tmp = wb;
      #pragma unroll
      for (int i = 0; i < 8; i++) Bs[(bn + i) * 40 + bk] = tmp[i];
    } else {
      const float* wg = (const float*)wv + (size_t)(k0 + bk) * 1024 + n0 + bn;
      float4 b0 = *(const float4*)wg, b1 = *(const float4*)(wg + 4);
      float tmp[8] = {b0.x,b0.y,b0.z,b0.w,b1.x,b1.y,b1.z,b1.w};
      #pragma unroll
      for (int i = 0; i < 8; i++) Bs[(bn + i) * 40 + bk] = f2b(tmp[i]);
    }
    __syncthreads();
    bf16x8 af = *(const bf16x8*)&As[(w * 16 + lr) * 40 + lq * 8];
    #pragma unroll
    for (int nb = 0; nb < 4; nb++) {
      bf16x8 bf = *(const bf16x8*)&Bs[(nb * 16 + lr) * 40 + lq * 8];
      acc[nb] = __builtin_amdgcn_mfma_f32_16x16x32_bf16(af, bf, acc[nb], 0, 0, 0);
    }
  }
  #pragma unroll
  for (int nb = 0; nb < 4; nb++) {
    #pragma unroll
    for (int r = 0; r < 4; r++) {
      const int row = m0 + w * 16 + lq * 4 + r;
      const int col = n0 + nb * 16 + lr;
      float val = acc[nb][r];
      if (isb) ((u16*)outv)[(size_t)row * 1024 + col] = f2b(val);
      else     ((float*)outv)[(size_t)row * 1024 + col] = val;
    }
  }
}

extern "C" void kernel_launch(void* const* d_in, const int* in_sizes, int n_in,
                              void* d_out, int out_size, void* d_ws, size_t ws_size,
                              hipStream_t stream)
{
  const void* x    = d_in[0];
  const void* wqkv = d_in[1];
  const void* wout = d_in[2];
  char* ws = (char*)d_ws;
  int* flag = (int*)ws;
  u16* Q   = (u16*)(ws + 4096);
  u16* K   = Q + 4194304;     // 2*16*2048*64
  u16* Vt  = K + 4194304;     // transposed: [bh][d][t]
  u16* ATT = Vt + 4194304;    // total ws use: ~32 MB + 4 KB

  sniff_kernel<<<1, 256, 0, stream>>>((const u16*)x, flag);
  qkv_rope_kernel<<<dim3(48, 64), 256, 0, stream>>>(x, wqkv, flag, Q, K, Vt);
  attn_kernel<<<512, 128, 0, stream>>>(Q, K, Vt, ATT);
  outproj_kernel<<<dim3(16, 64), 256, 0, stream>>>(ATT, wout, flag, d_out);
}

// Round 3
// 239.485 us; speedup vs baseline: 5.5812x; 1.6229x over previous
//
#include <hip/hip_runtime.h>
#include <hip/hip_bf16.h>
#include <stdint.h>

// B=2, T=2048, D=1024, H=16, hd=64.
// R3: pre-convert inputs to bf16 (+ transposed weights + RoPE table), m97-style
// 128x128 GEMMs with global_load_lds(16B) + XOR-swizzled LDS, attn at 8 waves/CU.

typedef unsigned short u16;
typedef short bf16x8 __attribute__((ext_vector_type(8)));
typedef float f32x4  __attribute__((ext_vector_type(4)));

#if defined(__has_builtin) && __has_builtin(__builtin_amdgcn_exp2f)
#define EXP2F(x) __builtin_amdgcn_exp2f(x)
#else
#define EXP2F(x) exp2f(x)
#endif

__device__ __forceinline__ u16 f2b(float f) {           // fp32 -> bf16 RNE
  uint32_t u = __float_as_uint(f);
  u += 0x7fffu + ((u >> 16) & 1u);
  return (u16)(u >> 16);
}
__device__ __forceinline__ uint32_t pk2(float a, float b) {
  return (uint32_t)f2b(a) | ((uint32_t)f2b(b) << 16);
}

// async global->LDS DMA, 16B per lane. LDS dest must be uniform-base + lane*16.
__device__ __forceinline__ void gl2lds16(const void* g, void* l) {
  __builtin_amdgcn_global_load_lds(
      (const __attribute__((address_space(1))) unsigned int*)g,
      (__attribute__((address_space(3))) unsigned int*)l, 16, 0, 0);
}

// ---------------------------------------------------------------- dtype sniff
__global__ void sniff_kernel(const u16* x, int* flag) {
  __shared__ int cnt;
  if (threadIdx.x == 0) cnt = 0;
  __syncthreads();
  int c = 0;
  for (int i = threadIdx.x; i < 4096; i += 256) {
    float a = fabsf(__uint_as_float(((uint32_t)x[2*i]) << 16));
    if (a > 1e-3f && a < 100.f) c++;
  }
  atomicAdd(&cnt, c);
  __syncthreads();
  if (threadIdx.x == 0) *flag = (cnt > 2048) ? 1 : 0;
}

// ------------------------------------------------- x -> bf16 (4096x1024)
__global__ __launch_bounds__(256) void convert_x_kernel(
    const void* __restrict__ xv, const int* __restrict__ flag, u16* __restrict__ Xb)
{
  const int isb = *flag;
  const size_t i = ((size_t)blockIdx.x * 256 + threadIdx.x) * 8;   // 8 elems/thread
  if (isb) {
    *(uint4*)&Xb[i] = *(const uint4*)((const u16*)xv + i);
  } else {
    const float* s = (const float*)xv + i;
    float4 a = *(const float4*)s, b = *(const float4*)(s + 4);
    uint4 p;
    p.x = pk2(a.x, a.y); p.y = pk2(a.z, a.w);
    p.z = pk2(b.x, b.y); p.w = pk2(b.z, b.w);
    *(uint4*)&Xb[i] = p;
  }
}

// ------------------------------------------------- W [K][N] -> Wt bf16 [N][K]
__global__ __launch_bounds__(256) void transpose_w_kernel(
    const void* __restrict__ src, u16* __restrict__ dst,
    int K, int N, const int* __restrict__ flag)
{
  __shared__ u16 Lt[64 * 72];
  const int isb = *flag;
  const int tid = threadIdx.x;
  const int n0 = blockIdx.x * 64, k0 = blockIdx.y * 64;
  const int r = tid >> 2, cseg = (tid & 3) << 4;
  u16 t[16];
  if (isb) {
    const u16* s = (const u16*)src + (size_t)(k0 + r) * N + n0 + cseg;
    *(uint4*)&t[0] = *(const uint4*)s;
    *(uint4*)&t[8] = *(const uint4*)(s + 8);
  } else {
    const float* s = (const float*)src + (size_t)(k0 + r) * N + n0 + cseg;
    #pragma unroll
    for (int j = 0; j < 4; j++) {
      float4 v = *(const float4*)(s + j * 4);
      t[j*4+0] = f2b(v.x); t[j*4+1] = f2b(v.y); t[j*4+2] = f2b(v.z); t[j*4+3] = f2b(v.w);
    }
  }
  #pragma unroll
  for (int j = 0; j < 16; j++) Lt[(cseg + j) * 72 + r] = t[j];
  __syncthreads();
  const int n = tid >> 2, kseg = (tid & 3) << 4;
  uint4 u0 = *(const uint4*)&Lt[n * 72 + kseg];
  uint4 u1 = *(const uint4*)&Lt[n * 72 + kseg + 8];
  u16* d = dst + (size_t)(n0 + n) * K + k0 + kseg;
  *(uint4*)d = u0;
  *(uint4*)(d + 8) = u1;
}

// ------------------------------------------------- RoPE table: CS[t*32+f] = {cos,sin}
__global__ __launch_bounds__(256) void rope_table_kernel(float2* __restrict__ CS) {
  const int idx = blockIdx.x * 256 + threadIdx.x;   // 65536
  const int t = idx >> 5, f = idx & 31;
  float invf = __expf(-(float)f * 0.2878231366242557f);  // ln(1e4)/32
  float th = (float)t * invf;
  float sn, cs;
  sincosf(th, &sn, &cs);
  CS[idx] = make_float2(cs, sn);
}

// ------------------------------------------------- QKV GEMM (NT, bf16) + RoPE
// Xb(4096,1024) x Wqkvt(3072,1024)^T. 128x128 tile, BK=64, 4 waves.
// LDS [row][seg], seg XOR-swizzled by row&7 (no padding; global_load_lds).
__global__ __launch_bounds__(256) void qkv_kernel(
    const u16* __restrict__ Xb, const u16* __restrict__ Wt,
    const float2* __restrict__ CS,
    u16* __restrict__ Q, u16* __restrict__ K, u16* __restrict__ Vt)
{
  __shared__ u16 As[128 * 64];
  __shared__ u16 Bs[128 * 64];
  const int tid = threadIdx.x;
  const int n0 = blockIdx.x * 128;
  const int m0 = blockIdx.y * 128;
  const int w = tid >> 6, l = tid & 63, lr = l & 15, lq = l >> 4;
  const int mrow0 = (w & 1) * 64;
  const int ncol0 = (w >> 1) * 64;

  // staging geometry: thread stages 16B; row = tid/8 + round*32, slot = tid&7,
  // global seg = slot ^ (row&7)
  const int srow = tid >> 3;
  const int gseg = (tid & 7) ^ (srow & 7);

  f32x4 acc[4][4] = {};

  for (int k0 = 0; k0 < 1024; k0 += 64) {
    __syncthreads();
    #pragma unroll
    for (int rd = 0; rd < 4; rd++) {
      const int row = srow + rd * 32;
      gl2lds16(Xb + (size_t)(m0 + row) * 1024 + k0 + gseg * 8, &As[tid * 8 + rd * 2048]);
      gl2lds16(Wt + (size_t)(n0 + row) * 1024 + k0 + gseg * 8, &Bs[tid * 8 + rd * 2048]);
    }
    __syncthreads();
    #pragma unroll
    for (int kc = 0; kc < 2; kc++) {
      bf16x8 af[4], bf[4];
      #pragma unroll
      for (int i = 0; i < 4; i++) {
        const int seg = ((kc << 2) | lq) ^ (lr & 7);
        af[i] = *(const bf16x8*)&As[(mrow0 + i * 16 + lr) * 64 + seg * 8];
        bf[i] = *(const bf16x8*)&Bs[(ncol0 + i * 16 + lr) * 64 + seg * 8];
      }
      #pragma unroll
      for (int mb = 0; mb < 4; mb++)
        #pragma unroll
        for (int nb = 0; nb < 4; nb++)
          acc[mb][nb] = __builtin_amdgcn_mfma_f32_16x16x32_bf16(af[mb], bf[nb], acc[mb][nb], 0, 0, 0);
    }
  }

  // epilogue: wave's 64 cols = one head of one section
  const int col0 = n0 + ncol0;
  const int sec = col0 >> 10;            // 0=q 1=k 2=v
  const int h = (col0 >> 6) & 15;
  if (sec == 2) {
    #pragma unroll
    for (int mb = 0; mb < 4; mb++) {
      const int row0 = m0 + mrow0 + mb * 16 + lq * 4;
      const int b = row0 >> 11, t0 = row0 & 2047;
      #pragma unroll
      for (int nb = 0; nb < 4; nb++) {
        const int d = nb * 16 + lr;
        uint2 uv;
        uv.x = pk2(acc[mb][nb][0], acc[mb][nb][1]);
        uv.y = pk2(acc[mb][nb][2], acc[mb][nb][3]);
        *(uint2*)&Vt[(((size_t)b * 16 + h) * 64 + d) * 2048 + t0] = uv;
      }
    }
  } else {
    u16* dst = (sec == 0) ? Q : K;
    const float qscale = 0.125f * 1.44269504f;   // 1/sqrt(hd) * log2(e), q only
    #pragma unroll
    for (int mb = 0; mb < 4; mb++) {
      const int row0 = m0 + mrow0 + mb * 16 + lq * 4;
      const int b = row0 >> 11, t0 = row0 & 2047;
      #pragma unroll
      for (int nb = 0; nb < 4; nb++) {
        const int d = nb * 16 + lr;
        const int f = d & 31;
        #pragma unroll
        for (int r = 0; r < 4; r++) {
          const int t = t0 + r;
          float2 cs = CS[t * 32 + f];
          float val = acc[mb][nb][r];
          float prt = __shfl_xor(val, 1, 64);   // partner col d^1 = lane lr^1
          float res = fmaf(val, cs.x, ((d & 1) ? prt : -prt) * cs.y);
          if (sec == 0) res *= qscale;
          dst[(((size_t)b * 16 + h) * 2048 + t) * 64 + d] = f2b(res);
        }
      }
    }
  }
}

// ------------------------------------------------- MFMA flash attention
// Block = 4 waves x 32 q-rows = 128 rows of one (b,h). Grid 512 -> 2 blocks/CU,
// 8 waves/CU. KV-tile 64. No max-sub: P = exp2(S), row-sum deferred.
__global__ __launch_bounds__(256) void attn_kernel(
    const u16* __restrict__ Q, const u16* __restrict__ K,
    const u16* __restrict__ Vt, u16* __restrict__ ATT)
{
  __shared__ u16 Ks[64 * 64];       // [s][d], XOR-swizzled segs
  __shared__ u16 Vs[64 * 64];       // [d][s], XOR-swizzled segs
  __shared__ u16 Ps[4 * 32 * 72];   // per-wave [m][s] padded
  const int tid = threadIdx.x;
  const int w = tid >> 6, l = tid & 63, lr = l & 15, lq = l >> 4;
  const int bh = blockIdx.x >> 4;
  const int qt = blockIdx.x & 15;
  const size_t base = (size_t)bh * (2048 * 64);
  const int qrow0 = qt * 128 + w * 32;
  u16* Psw = Ps + w * (32 * 72);

  bf16x8 qf[2][2];
  #pragma unroll
  for (int mb = 0; mb < 2; mb++)
    #pragma unroll
    for (int kc = 0; kc < 2; kc++)
      qf[mb][kc] = *(const bf16x8*)(Q + base + (size_t)(qrow0 + mb * 16 + lr) * 64 + kc * 32 + lq * 8);

  f32x4 oa[2][4] = {};
  f32x4 lsum[2] = {};

  const int srow = tid >> 3;              // staging: row 0..31 (+32 per round)
  const int gseg = (tid & 7) ^ (srow & 7);

  #pragma unroll 1
  for (int s0 = 0; s0 < 2048; s0 += 64) {
    __syncthreads();
    #pragma unroll
    for (int rd = 0; rd < 2; rd++) {
      const int row = srow + rd * 32;
      const int gs = (tid & 7) ^ (row & 7);
      gl2lds16(K + base + (size_t)(s0 + row) * 64 + gs * 8, &Ks[tid * 8 + rd * 2048]);
      gl2lds16(Vt + base + (size_t)row * 2048 + s0 + gs * 8, &Vs[tid * 8 + rd * 2048]);
    }
    __syncthreads();

    bf16x8 kf[4][2], vf[4][2];
    #pragma unroll
    for (int nb = 0; nb < 4; nb++)
      #pragma unroll
      for (int kc = 0; kc < 2; kc++) {
        const int seg = ((kc << 2) | lq) ^ (lr & 7);
        kf[nb][kc] = *(const bf16x8*)&Ks[(nb * 16 + lr) * 64 + seg * 8];
        vf[nb][kc] = *(const bf16x8*)&Vs[(nb * 16 + lr) * 64 + seg * 8];
      }

    const int ev = (lr & 1) == 0;
    #pragma unroll
    for (int mb = 0; mb < 2; mb++) {
      #pragma unroll
      for (int nb = 0; nb < 4; nb++) {
        f32x4 s = {};
        s = __builtin_amdgcn_mfma_f32_16x16x32_bf16(qf[mb][0], kf[nb][0], s, 0, 0, 0);
        s = __builtin_amdgcn_mfma_f32_16x16x32_bf16(qf[mb][1], kf[nb][1], s, 0, 0, 0);
        float e0 = EXP2F(s[0]), e1 = EXP2F(s[1]), e2 = EXP2F(s[2]), e3 = EXP2F(s[3]);
        lsum[mb][0] += e0; lsum[mb][1] += e1;
        lsum[mb][2] += e2; lsum[mb][3] += e3;
        uint32_t p01 = (uint32_t)f2b(e0) | ((uint32_t)f2b(e1) << 16);
        uint32_t p23 = (uint32_t)f2b(e2) | ((uint32_t)f2b(e3) << 16);
        uint32_t pp01 = (uint32_t)__shfl_xor((int)p01, 1, 64);
        uint32_t pp23 = (uint32_t)__shfl_xor((int)p23, 1, 64);
        uint32_t wA = ev ? ((p01 & 0xffffu) | (pp01 << 16))
                         : ((pp23 & 0xffffu) | (p23 << 16));
        uint32_t wB = ev ? ((p01 >> 16) | (pp01 & 0xffff0000u))
                         : ((pp23 >> 16) | (p23 & 0xffff0000u));
        const int row0 = mb * 16 + lq * 4 + (ev ? 0 : 2);
        const int c = nb * 16 + (lr & ~1);
        *(uint32_t*)&Psw[row0 * 72 + c] = wA;
        *(uint32_t*)&Psw[(row0 + 1) * 72 + c] = wB;
      }
    }

    #pragma unroll
    for (int mb = 0; mb < 2; mb++) {
      bf16x8 pf0 = *(const bf16x8*)&Psw[(mb * 16 + lr) * 72 + lq * 8];
      bf16x8 pf1 = *(const bf16x8*)&Psw[(mb * 16 + lr) * 72 + 32 + lq * 8];
      #pragma unroll
      for (int nb = 0; nb < 4; nb++) {
        oa[mb][nb] = __builtin_amdgcn_mfma_f32_16x16x32_bf16(pf0, vf[nb][0], oa[mb][nb], 0, 0, 0);
        oa[mb][nb] = __builtin_amdgcn_mfma_f32_16x16x32_bf16(pf1, vf[nb][1], oa[mb][nb], 0, 0, 0);
      }
    }
  }

  const int b = bh >> 4, h = bh & 15;
  #pragma unroll
  for (int mb = 0; mb < 2; mb++) {
    #pragma unroll
    for (int r = 0; r < 4; r++) {
      float v = lsum[mb][r];
      v += __shfl_xor(v, 1, 64);
      v += __shfl_xor(v, 2, 64);
      v += __shfl_xor(v, 4, 64);
      v += __shfl_xor(v, 8, 64);
      lsum[mb][r] = 1.f / v;
    }
    #pragma unroll
    for (int nb = 0; nb < 4; nb++) {
      const int d = nb * 16 + lr;
      #pragma unroll
      for (int r = 0; r < 4; r++) {
        const int t = qrow0 + mb * 16 + lq * 4 + r;
        ATT[((size_t)(b * 2048 + t)) * 1024 + h * 64 + d] = f2b(oa[mb][nb][r] * lsum[mb][r]);
      }
    }
  }
}

// ------------------------------------------------- output projection (NT, bf16)
__global__ __launch_bounds__(256) void outproj_kernel(
    const u16* __restrict__ A, const u16* __restrict__ Wt,
    const int* __restrict__ flag, void* __restrict__ outv)
{
  __shared__ u16 As[128 * 64];
  __shared__ u16 Bs[128 * 64];
  const int isb = *flag;
  const int tid = threadIdx.x;
  const int n0 = blockIdx.x * 128;
  const int m0 = blockIdx.y * 128;
  const int w = tid >> 6, l = tid & 63, lr = l & 15, lq = l >> 4;
  const int mrow0 = (w & 1) * 64;
  const int ncol0 = (w >> 1) * 64;
  const int srow = tid >> 3;
  const int gseg = (tid & 7) ^ (srow & 7);

  f32x4 acc[4][4] = {};

  for (int k0 = 0; k0 < 1024; k0 += 64) {
    __syncthreads();
    #pragma unroll
    for (int rd = 0; rd < 4; rd++) {
      const int row = srow + rd * 32;
      gl2lds16(A + (size_t)(m0 + row) * 1024 + k0 + gseg * 8, &As[tid * 8 + rd * 2048]);
      gl2lds16(Wt + (size_t)(n0 + row) * 1024 + k0 + gseg * 8, &Bs[tid * 8 + rd * 2048]);
    }
    __syncthreads();
    #pragma unroll
    for (int kc = 0; kc < 2; kc++) {
      bf16x8 af[4], bf[4];
      #pragma unroll
      for (int i = 0; i < 4; i++) {
        const int seg = ((kc << 2) | lq) ^ (lr & 7);
        af[i] = *(const bf16x8*)&As[(mrow0 + i * 16 + lr) * 64 + seg * 8];
        bf[i] = *(const bf16x8*)&Bs[(ncol0 + i * 16 + lr) * 64 + seg * 8];
      }
      #pragma unroll
      for (int mb = 0; mb < 4; mb++)
        #pragma unroll
        for (int nb = 0; nb < 4; nb++)
          acc[mb][nb] = __builtin_amdgcn_mfma_f32_16x16x32_bf16(af[mb], bf[nb], acc[mb][nb], 0, 0, 0);
    }
  }
  #pragma unroll
  for (int mb = 0; mb < 4; mb++) {
    const int row = m0 + mrow0 + mb * 16 + lq * 4;
    #pragma unroll
    for (int nb = 0; nb < 4; nb++) {
      const int col = n0 + ncol0 + nb * 16 + lr;
      #pragma unroll
      for (int r = 0; r < 4; r++) {
        float val = acc[mb][nb][r];
        if (isb) ((u16*)outv)[(size_t)(row + r) * 1024 + col] = f2b(val);
        else     ((float*)outv)[(size_t)(row + r) * 1024 + col] = val;
      }
    }
  }
}

extern "C" void kernel_launch(void* const* d_in, const int* in_sizes, int n_in,
                              void* d_out, int out_size, void* d_ws, size_t ws_size,
                              hipStream_t stream)
{
  const void* x    = d_in[0];
  const void* wqkv = d_in[1];
  const void* wout = d_in[2];
  char* ws = (char*)d_ws;
  const size_t MB = 1024 * 1024;
  int*    flag   = (int*)ws;
  float2* CS     = (float2*)(ws + 1024);            // 512 KB
  u16*    Xb     = (u16*)(ws + 1 * MB);             // 8 MB  (aliased by ATT later)
  u16*    ATT    = Xb;
  u16*    Wqkvt  = (u16*)(ws + 9 * MB);             // 6 MB
  u16*    Woutt  = (u16*)(ws + 15 * MB);            // 2 MB
  u16*    Q      = (u16*)(ws + 17 * MB);            // 8 MB
  u16*    K      = (u16*)(ws + 25 * MB);            // 8 MB
  u16*    Vt     = (u16*)(ws + 33 * MB);            // 8 MB -> total 41 MB

  sniff_kernel<<<1, 256, 0, stream>>>((const u16*)x, flag);
  convert_x_kernel<<<2048, 256, 0, stream>>>(x, flag, Xb);
  transpose_w_kernel<<<dim3(48, 16), 256, 0, stream>>>(wqkv, Wqkvt, 1024, 3072, flag);
  transpose_w_kernel<<<dim3(16, 16), 256, 0, stream>>>(wout, Woutt, 1024, 1024, flag);
  rope_table_kernel<<<256, 256, 0, stream>>>(CS);
  qkv_kernel<<<dim3(24, 32), 256, 0, stream>>>(Xb, Wqkvt, CS, Q, K, Vt);
  attn_kernel<<<512, 256, 0, stream>>>(Q, K, Vt, ATT);
  outproj_kernel<<<dim3(8, 32), 256, 0, stream>>>(ATT, Woutt, flag, d_out);
}

// Round 4
// 226.790 us; speedup vs baseline: 5.8936x; 1.0560x over previous
//
#include <hip/hip_runtime.h>
#include <hip/hip_bf16.h>
#include <stdint.h>

// B=2, T=2048, D=1024, H=16, hd=64.
// R4: attention rebuilt: S^T formulation (no shuffle transpose), double-buffered
// K/V DMA staging (1 barrier/tile), optional split-s x2 with fp32 partials.

typedef unsigned short u16;
typedef short bf16x8 __attribute__((ext_vector_type(8)));
typedef float f32x4  __attribute__((ext_vector_type(4)));

#if defined(__has_builtin) && __has_builtin(__builtin_amdgcn_exp2f)
#define EXP2F(x) __builtin_amdgcn_exp2f(x)
#else
#define EXP2F(x) exp2f(x)
#endif

__device__ __forceinline__ u16 f2b(float f) {           // fp32 -> bf16 RNE
  uint32_t u = __float_as_uint(f);
  u += 0x7fffu + ((u >> 16) & 1u);
  return (u16)(u >> 16);
}
__device__ __forceinline__ uint32_t pk2(float a, float b) {
  return (uint32_t)f2b(a) | ((uint32_t)f2b(b) << 16);
}
__device__ __forceinline__ uint32_t pkbf(float a, float b) {
  __hip_bfloat162 h = __float22bfloat162_rn(make_float2(a, b));
  union { __hip_bfloat162 h2; uint32_t u; } cv; cv.h2 = h;
  return cv.u;
}

// async global->LDS DMA, 16B per lane. LDS dest must be uniform-base + lane*16.
__device__ __forceinline__ void gl2lds16(const void* g, void* l) {
  __builtin_amdgcn_global_load_lds(
      (const __attribute__((address_space(1))) unsigned int*)g,
      (__attribute__((address_space(3))) unsigned int*)l, 16, 0, 0);
}

// ---------------------------------------------------------------- dtype sniff
__global__ void sniff_kernel(const u16* x, int* flag) {
  __shared__ int cnt;
  if (threadIdx.x == 0) cnt = 0;
  __syncthreads();
  int c = 0;
  for (int i = threadIdx.x; i < 4096; i += 256) {
    float a = fabsf(__uint_as_float(((uint32_t)x[2*i]) << 16));
    if (a > 1e-3f && a < 100.f) c++;
  }
  atomicAdd(&cnt, c);
  __syncthreads();
  if (threadIdx.x == 0) *flag = (cnt > 2048) ? 1 : 0;
}

// ------------------------------------------------- x -> bf16 (4096x1024)
__global__ __launch_bounds__(256) void convert_x_kernel(
    const void* __restrict__ xv, const int* __restrict__ flag, u16* __restrict__ Xb)
{
  const int isb = *flag;
  const size_t i = ((size_t)blockIdx.x * 256 + threadIdx.x) * 8;
  if (isb) {
    *(uint4*)&Xb[i] = *(const uint4*)((const u16*)xv + i);
  } else {
    const float* s = (const float*)xv + i;
    float4 a = *(const float4*)s, b = *(const float4*)(s + 4);
    uint4 p;
    p.x = pk2(a.x, a.y); p.y = pk2(a.z, a.w);
    p.z = pk2(b.x, b.y); p.w = pk2(b.z, b.w);
    *(uint4*)&Xb[i] = p;
  }
}

// ------------------------------------------------- W [K][N] -> Wt bf16 [N][K]
__global__ __launch_bounds__(256) void transpose_w_kernel(
    const void* __restrict__ src, u16* __restrict__ dst,
    int K, int N, const int* __restrict__ flag)
{
  __shared__ u16 Lt[64 * 72];
  const int isb = *flag;
  const int tid = threadIdx.x;
  const int n0 = blockIdx.x * 64, k0 = blockIdx.y * 64;
  const int r = tid >> 2, cseg = (tid & 3) << 4;
  u16 t[16];
  if (isb) {
    const u16* s = (const u16*)src + (size_t)(k0 + r) * N + n0 + cseg;
    *(uint4*)&t[0] = *(const uint4*)s;
    *(uint4*)&t[8] = *(const uint4*)(s + 8);
  } else {
    const float* s = (const float*)src + (size_t)(k0 + r) * N + n0 + cseg;
    #pragma unroll
    for (int j = 0; j < 4; j++) {
      float4 v = *(const float4*)(s + j * 4);
      t[j*4+0] = f2b(v.x); t[j*4+1] = f2b(v.y); t[j*4+2] = f2b(v.z); t[j*4+3] = f2b(v.w);
    }
  }
  #pragma unroll
  for (int j = 0; j < 16; j++) Lt[(cseg + j) * 72 + r] = t[j];
  __syncthreads();
  const int n = tid >> 2, kseg = (tid & 3) << 4;
  uint4 u0 = *(const uint4*)&Lt[n * 72 + kseg];
  uint4 u1 = *(const uint4*)&Lt[n * 72 + kseg + 8];
  u16* d = dst + (size_t)(n0 + n) * K + k0 + kseg;
  *(uint4*)d = u0;
  *(uint4*)(d + 8) = u1;
}

// ------------------------------------------------- RoPE table: CS[t*32+f] = {cos,sin}
__global__ __launch_bounds__(256) void rope_table_kernel(float2* __restrict__ CS) {
  const int idx = blockIdx.x * 256 + threadIdx.x;   // 65536
  const int t = idx >> 5, f = idx & 31;
  float invf = __expf(-(float)f * 0.2878231366242557f);  // ln(1e4)/32
  float th = (float)t * invf;
  float sn, cs;
  sincosf(th, &sn, &cs);
  CS[idx] = make_float2(cs, sn);
}

// ------------------------------------------------- QKV GEMM (NT, bf16) + RoPE
__global__ __launch_bounds__(256) void qkv_kernel(
    const u16* __restrict__ Xb, const u16* __restrict__ Wt,
    const float2* __restrict__ CS,
    u16* __restrict__ Q, u16* __restrict__ K, u16* __restrict__ Vt)
{
  __shared__ u16 As[128 * 64];
  __shared__ u16 Bs[128 * 64];
  const int tid = threadIdx.x;
  const int n0 = blockIdx.x * 128;
  const int m0 = blockIdx.y * 128;
  const int w = tid >> 6, l = tid & 63, lr = l & 15, lq = l >> 4;
  const int mrow0 = (w & 1) * 64;
  const int ncol0 = (w >> 1) * 64;
  const int srow = tid >> 3;
  const int gseg = (tid & 7) ^ (srow & 7);

  f32x4 acc[4][4] = {};

  for (int k0 = 0; k0 < 1024; k0 += 64) {
    __syncthreads();
    #pragma unroll
    for (int rd = 0; rd < 4; rd++) {
      const int row = srow + rd * 32;
      gl2lds16(Xb + (size_t)(m0 + row) * 1024 + k0 + gseg * 8, &As[tid * 8 + rd * 2048]);
      gl2lds16(Wt + (size_t)(n0 + row) * 1024 + k0 + gseg * 8, &Bs[tid * 8 + rd * 2048]);
    }
    __syncthreads();
    #pragma unroll
    for (int kc = 0; kc < 2; kc++) {
      bf16x8 af[4], bf[4];
      #pragma unroll
      for (int i = 0; i < 4; i++) {
        const int seg = ((kc << 2) | lq) ^ (lr & 7);
        af[i] = *(const bf16x8*)&As[(mrow0 + i * 16 + lr) * 64 + seg * 8];
        bf[i] = *(const bf16x8*)&Bs[(ncol0 + i * 16 + lr) * 64 + seg * 8];
      }
      #pragma unroll
      for (int mb = 0; mb < 4; mb++)
        #pragma unroll
        for (int nb = 0; nb < 4; nb++)
          acc[mb][nb] = __builtin_amdgcn_mfma_f32_16x16x32_bf16(af[mb], bf[nb], acc[mb][nb], 0, 0, 0);
    }
  }

  const int col0 = n0 + ncol0;
  const int sec = col0 >> 10;            // 0=q 1=k 2=v
  const int h = (col0 >> 6) & 15;
  if (sec == 2) {
    #pragma unroll
    for (int mb = 0; mb < 4; mb++) {
      const int row0 = m0 + mrow0 + mb * 16 + lq * 4;
      const int b = row0 >> 11, t0 = row0 & 2047;
      #pragma unroll
      for (int nb = 0; nb < 4; nb++) {
        const int d = nb * 16 + lr;
        uint2 uv;
        uv.x = pk2(acc[mb][nb][0], acc[mb][nb][1]);
        uv.y = pk2(acc[mb][nb][2], acc[mb][nb][3]);
        *(uint2*)&Vt[(((size_t)b * 16 + h) * 64 + d) * 2048 + t0] = uv;
      }
    }
  } else {
    u16* dst = (sec == 0) ? Q : K;
    const float qscale = 0.125f * 1.44269504f;   // 1/sqrt(hd) * log2(e), q only
    #pragma unroll
    for (int mb = 0; mb < 4; mb++) {
      const int row0 = m0 + mrow0 + mb * 16 + lq * 4;
      const int b = row0 >> 11, t0 = row0 & 2047;
      #pragma unroll
      for (int nb = 0; nb < 4; nb++) {
        const int d = nb * 16 + lr;
        const int f = d & 31;
        #pragma unroll
        for (int r = 0; r < 4; r++) {
          const int t = t0 + r;
          float2 cs = CS[t * 32 + f];
          float val = acc[mb][nb][r];
          float prt = __shfl_xor(val, 1, 64);   // partner col d^1 = lane lr^1
          float res = fmaf(val, cs.x, ((d & 1) ? prt : -prt) * cs.y);
          if (sec == 0) res *= qscale;
          dst[(((size_t)b * 16 + h) * 2048 + t) * 64 + d] = f2b(res);
        }
      }
    }
  }
}

// ------------------------------------------------- MFMA flash attention (R4)
// Block = 4 waves x 32 q-rows = 128 rows of one (b,h). gridDim.y = ns s-splits.
// S^T = mfma(Kfrag, Qfrag) -> lane holds 4 consecutive s for fixed m -> pack
// in-lane, ds_write_b64 into P[m][s]; PV reads B-frags contiguously.
// Double-buffered K/V staging: one barrier per tile, DMA overlaps compute.
__global__ __launch_bounds__(256, 3) void attn_kernel(
    const u16* __restrict__ Q, const u16* __restrict__ K,
    const u16* __restrict__ Vt, u16* __restrict__ ATT,
    float* __restrict__ Op, float* __restrict__ Ls)
{
  __shared__ u16 Ks[2][64 * 64];
  __shared__ u16 Vs[2][64 * 64];
  __shared__ u16 Ps[4][32 * 72];
  const int tid = threadIdx.x;
  const int w = tid >> 6, l = tid & 63, lr = l & 15, lq = l >> 4;
  const int bh = blockIdx.x >> 4;
  const int qt = blockIdx.x & 15;
  const int ns = gridDim.y, sh = blockIdx.y;
  const int slen = 2048 / ns;
  const int sbeg = sh * slen;
  const size_t base = (size_t)bh * (2048 * 64);
  const int qrow0 = qt * 128 + w * 32;
  u16* Psw = &Ps[w][0];

  // Q fragments (B-operand: n=m=lane&15, k=quad*8+j)
  bf16x8 qf[2][2];
  #pragma unroll
  for (int mb = 0; mb < 2; mb++)
    #pragma unroll
    for (int kc = 0; kc < 2; kc++)
      qf[mb][kc] = *(const bf16x8*)(Q + base + (size_t)(qrow0 + mb * 16 + lr) * 64 + kc * 32 + lq * 8);

  f32x4 oa[4][2] = {};       // O^T: [db][mb], row=d, col=m
  float lsum[2] = {0.f, 0.f};

  const int srow = tid >> 3;

  auto stage = [&](int buf, int s0) {
    #pragma unroll
    for (int rd = 0; rd < 2; rd++) {
      const int row = srow + rd * 32;
      const int gs = (tid & 7) ^ (row & 7);
      gl2lds16(K + base + (size_t)(s0 + row) * 64 + gs * 8, &Ks[buf][tid * 8 + rd * 2048]);
      gl2lds16(Vt + base + (size_t)row * 2048 + s0 + gs * 8, &Vs[buf][tid * 8 + rd * 2048]);
    }
  };

  stage(0, sbeg);
  const int nt = slen >> 6;

  #pragma unroll 1
  for (int t = 0; t < nt; t++) {
    const int buf = t & 1;
    __syncthreads();                       // drains DMA for buf, fences prev reads
    if (t + 1 < nt) stage(buf ^ 1, sbeg + (t + 1) * 64);

    bf16x8 kf[4][2], vf[4][2];
    #pragma unroll
    for (int nb = 0; nb < 4; nb++)
      #pragma unroll
      for (int kc = 0; kc < 2; kc++) {
        const int seg = ((kc << 2) | lq) ^ (lr & 7);
        kf[nb][kc] = *(const bf16x8*)&Ks[buf][(nb * 16 + lr) * 64 + seg * 8];
        vf[nb][kc] = *(const bf16x8*)&Vs[buf][(nb * 16 + lr) * 64 + seg * 8];
      }

    // S^T blocks: row s = sb*16+quad*4+r, col m = mb*16+lane&15
    #pragma unroll
    for (int sb = 0; sb < 4; sb++) {
      #pragma unroll
      for (int mb = 0; mb < 2; mb++) {
        f32x4 st = {};
        st = __builtin_amdgcn_mfma_f32_16x16x32_bf16(kf[sb][0], qf[mb][0], st, 0, 0, 0);
        st = __builtin_amdgcn_mfma_f32_16x16x32_bf16(kf[sb][1], qf[mb][1], st, 0, 0, 0);
        float e0 = EXP2F(st[0]), e1 = EXP2F(st[1]), e2 = EXP2F(st[2]), e3 = EXP2F(st[3]);
        lsum[mb] += (e0 + e1) + (e2 + e3);
        uint2 pp;
        pp.x = pkbf(e0, e1);
        pp.y = pkbf(e2, e3);
        *(uint2*)&Psw[(mb * 16 + lr) * 72 + sb * 16 + lq * 4] = pp;   // P[m][s]
      }
    }

    // O^T += V^T · P^T : A = Vt-frag (rows d), B = P^T (cols m), k = s
    #pragma unroll
    for (int mb = 0; mb < 2; mb++) {
      bf16x8 pf0 = *(const bf16x8*)&Psw[(mb * 16 + lr) * 72 + lq * 8];
      bf16x8 pf1 = *(const bf16x8*)&Psw[(mb * 16 + lr) * 72 + 32 + lq * 8];
      #pragma unroll
      for (int db = 0; db < 4; db++) {
        oa[db][mb] = __builtin_amdgcn_mfma_f32_16x16x32_bf16(vf[db][0], pf0, oa[db][mb], 0, 0, 0);
        oa[db][mb] = __builtin_amdgcn_mfma_f32_16x16x32_bf16(vf[db][1], pf1, oa[db][mb], 0, 0, 0);
      }
    }
  }

  // reduce row sums across quads (lanes lr, lr+16, lr+32, lr+48)
  #pragma unroll
  for (int mb = 0; mb < 2; mb++) {
    float v = lsum[mb];
    v += __shfl_xor(v, 16, 64);
    v += __shfl_xor(v, 32, 64);
    lsum[mb] = v;
  }

  const int b = bh >> 4, h = bh & 15;
  if (ns == 1) {
    #pragma unroll
    for (int mb = 0; mb < 2; mb++) {
      const float inv = 1.f / lsum[mb];
      const int t = qrow0 + mb * 16 + lr;
      u16* dst = ATT + ((size_t)(b * 2048 + t)) * 1024 + h * 64;
      #pragma unroll
      for (int db = 0; db < 4; db++) {
        uint2 u;
        u.x = pkbf(oa[db][mb][0] * inv, oa[db][mb][1] * inv);
        u.y = pkbf(oa[db][mb][2] * inv, oa[db][mb][3] * inv);
        *(uint2*)&dst[db * 16 + lq * 4] = u;
      }
    }
  } else {
    float* op = Op + (size_t)sh * (65536ull * 64);
    #pragma unroll
    for (int mb = 0; mb < 2; mb++) {
      const size_t row = (size_t)bh * 2048 + qrow0 + mb * 16 + lr;
      #pragma unroll
      for (int db = 0; db < 4; db++)
        *(f32x4*)&op[row * 64 + db * 16 + lq * 4] = oa[db][mb];
      if (lq == 0) Ls[(size_t)sh * 65536 + row] = lsum[mb];
    }
  }
}

// ------------------------------------------------- combine s-split partials
__global__ __launch_bounds__(256) void combine_kernel(
    const float* __restrict__ Op, const float* __restrict__ Ls, u16* __restrict__ ATT)
{
  const int idx = blockIdx.x * 256 + threadIdx.x;   // 524288
  const int R = idx >> 3;
  const int c = (idx & 7) * 8;
  const float* p0 = Op + (size_t)R * 64 + c;
  const float* p1 = p0 + 65536ull * 64;
  f32x4 a0 = *(const f32x4*)p0, a1 = *(const f32x4*)(p0 + 4);
  f32x4 b0 = *(const f32x4*)p1, b1 = *(const f32x4*)(p1 + 4);
  const float inv = 1.f / (Ls[R] + Ls[65536 + R]);
  const int bh = R >> 11, trow = R & 2047;
  const int b = bh >> 4, h = bh & 15;
  u16* d = ATT + ((size_t)(b * 2048 + trow)) * 1024 + h * 64 + c;
  uint4 u;
  u.x = pkbf((a0[0] + b0[0]) * inv, (a0[1] + b0[1]) * inv);
  u.y = pkbf((a0[2] + b0[2]) * inv, (a0[3] + b0[3]) * inv);
  u.z = pkbf((a1[0] + b1[0]) * inv, (a1[1] + b1[1]) * inv);
  u.w = pkbf((a1[2] + b1[2]) * inv, (a1[3] + b1[3]) * inv);
  *(uint4*)d = u;
}

// ------------------------------------------------- output projection (NT, bf16)
__global__ __launch_bounds__(256) void outproj_kernel(
    const u16* __restrict__ A, const u16* __restrict__ Wt,
    const int* __restrict__ flag, void* __restrict__ outv)
{
  __shared__ u16 As[128 * 64];
  __shared__ u16 Bs[128 * 64];
  const int isb = *flag;
  const int tid = threadIdx.x;
  const int n0 = blockIdx.x * 128;
  const int m0 = blockIdx.y * 128;
  const int w = tid >> 6, l = tid & 63, lr = l & 15, lq = l >> 4;
  const int mrow0 = (w & 1) * 64;
  const int ncol0 = (w >> 1) * 64;
  const int srow = tid >> 3;
  const int gseg = (tid & 7) ^ (srow & 7);

  f32x4 acc[4][4] = {};

  for (int k0 = 0; k0 < 1024; k0 += 64) {
    __syncthreads();
    #pragma unroll
    for (int rd = 0; rd < 4; rd++) {
      const int row = srow + rd * 32;
      gl2lds16(A + (size_t)(m0 + row) * 1024 + k0 + gseg * 8, &As[tid * 8 + rd * 2048]);
      gl2lds16(Wt + (size_t)(n0 + row) * 1024 + k0 + gseg * 8, &Bs[tid * 8 + rd * 2048]);
    }
    __syncthreads();
    #pragma unroll
    for (int kc = 0; kc < 2; kc++) {
      bf16x8 af[4], bf[4];
      #pragma unroll
      for (int i = 0; i < 4; i++) {
        const int seg = ((kc << 2) | lq) ^ (lr & 7);
        af[i] = *(const bf16x8*)&As[(mrow0 + i * 16 + lr) * 64 + seg * 8];
        bf[i] = *(const bf16x8*)&Bs[(ncol0 + i * 16 + lr) * 64 + seg * 8];
      }
      #pragma unroll
      for (int mb = 0; mb < 4; mb++)
        #pragma unroll
        for (int nb = 0; nb < 4; nb++)
          acc[mb][nb] = __builtin_amdgcn_mfma_f32_16x16x32_bf16(af[mb], bf[nb], acc[mb][nb], 0, 0, 0);
    }
  }
  #pragma unroll
  for (int mb = 0; mb < 4; mb++) {
    const int row = m0 + mrow0 + mb * 16 + lq * 4;
    #pragma unroll
    for (int nb = 0; nb < 4; nb++) {
      const int col = n0 + ncol0 + nb * 16 + lr;
      #pragma unroll
      for (int r = 0; r < 4; r++) {
        float val = acc[mb][nb][r];
        if (isb) ((u16*)outv)[(size_t)(row + r) * 1024 + col] = f2b(val);
        else     ((float*)outv)[(size_t)(row + r) * 1024 + col] = val;
      }
    }
  }
}

extern "C" void kernel_launch(void* const* d_in, const int* in_sizes, int n_in,
                              void* d_out, int out_size, void* d_ws, size_t ws_size,
                              hipStream_t stream)
{
  const void* x    = d_in[0];
  const void* wqkv = d_in[1];
  const void* wout = d_in[2];
  char* ws = (char*)d_ws;
  const size_t MB = 1024 * 1024;
  int*    flag   = (int*)ws;
  float2* CS     = (float2*)(ws + 1024);            // 512 KB
  u16*    Xb     = (u16*)(ws + 1 * MB);             // 8 MB  (aliased by ATT)
  u16*    ATT    = Xb;
  u16*    Wqkvt  = (u16*)(ws + 9 * MB);             // 6 MB
  u16*    Woutt  = (u16*)(ws + 15 * MB);            // 2 MB
  u16*    Q      = (u16*)(ws + 17 * MB);            // 8 MB
  u16*    K      = (u16*)(ws + 25 * MB);            // 8 MB
  u16*    Vt     = (u16*)(ws + 33 * MB);            // 8 MB
  float*  Op     = (float*)(ws + 41 * MB);          // 32 MB (ns=2)
  float*  Ls     = (float*)(ws + 75 * MB);          // 0.5 MB

  const bool split = ws_size >= 76 * MB;            // deterministic across calls
  const int ns = split ? 2 : 1;

  sniff_kernel<<<1, 256, 0, stream>>>((const u16*)x, flag);
  convert_x_kernel<<<2048, 256, 0, stream>>>(x, flag, Xb);
  transpose_w_kernel<<<dim3(48, 16), 256, 0, stream>>>(wqkv, Wqkvt, 1024, 3072, flag);
  transpose_w_kernel<<<dim3(16, 16), 256, 0, stream>>>(wout, Woutt, 1024, 1024, flag);
  rope_table_kernel<<<256, 256, 0, stream>>>(CS);
  qkv_kernel<<<dim3(24, 32), 256, 0, stream>>>(Xb, Wqkvt, CS, Q, K, Vt);
  attn_kernel<<<dim3(512, ns), 256, 0, stream>>>(Q, K, Vt, ATT, Op, Ls);
  if (split)
    combine_kernel<<<2048, 256, 0, stream>>>(Op, Ls, ATT);
  outproj_kernel<<<dim3(8, 32), 256, 0, stream>>>(ATT, Woutt, flag, d_out);
}

// Round 5
// 214.622 us; speedup vs baseline: 6.2278x; 1.0567x over previous
//
#include <hip/hip_runtime.h>
#include <hip/hip_bf16.h>
#include <stdint.h>

// B=2, T=2048, D=1024, H=16, hd=64.
// R5: attn with 64 q-rows/wave (64 MFMA per barrier-segment), P in XOR-swizzled
// 64-stride LDS (total exactly 64KB); fused prep kernel (convert+transpose+rope).

typedef unsigned short u16;
typedef short bf16x8 __attribute__((ext_vector_type(8)));
typedef float f32x4  __attribute__((ext_vector_type(4)));

#if defined(__has_builtin) && __has_builtin(__builtin_amdgcn_exp2f)
#define EXP2F(x) __builtin_amdgcn_exp2f(x)
#else
#define EXP2F(x) exp2f(x)
#endif

__device__ __forceinline__ u16 f2b(float f) {           // fp32 -> bf16 RNE
  uint32_t u = __float_as_uint(f);
  u += 0x7fffu + ((u >> 16) & 1u);
  return (u16)(u >> 16);
}
__device__ __forceinline__ uint32_t pk2(float a, float b) {
  return (uint32_t)f2b(a) | ((uint32_t)f2b(b) << 16);
}
__device__ __forceinline__ uint32_t pkbf(float a, float b) {  // v_cvt_pk_bf16_f32
  __hip_bfloat162 h = __float22bfloat162_rn(make_float2(a, b));
  union { __hip_bfloat162 h2; uint32_t u; } cv; cv.h2 = h;
  return cv.u;
}

// async global->LDS DMA, 16B per lane. LDS dest must be uniform-base + lane*16.
__device__ __forceinline__ void gl2lds16(const void* g, void* l) {
  __builtin_amdgcn_global_load_lds(
      (const __attribute__((address_space(1))) unsigned int*)g,
      (__attribute__((address_space(3))) unsigned int*)l, 16, 0, 0);
}

// ---------------------------------------------------------------- dtype sniff
__global__ void sniff_kernel(const u16* x, int* flag) {
  __shared__ int cnt;
  if (threadIdx.x == 0) cnt = 0;
  __syncthreads();
  int c = 0;
  for (int i = threadIdx.x; i < 4096; i += 256) {
    float a = fabsf(__uint_as_float(((uint32_t)x[2*i]) << 16));
    if (a > 1e-3f && a < 100.f) c++;
  }
  atomicAdd(&cnt, c);
  __syncthreads();
  if (threadIdx.x == 0) *flag = (cnt > 2048) ? 1 : 0;
}

// ------------------------------------------------- 64x64 transpose helper
__device__ __forceinline__ void tr_tile(const void* src, u16* dst, int Kd, int N,
                                        int n0, int k0, int isb, u16* Lt, int tid)
{
  const int r = tid >> 2, cseg = (tid & 3) << 4;
  u16 t[16];
  if (isb) {
    const u16* s = (const u16*)src + (size_t)(k0 + r) * N + n0 + cseg;
    *(uint4*)&t[0] = *(const uint4*)s;
    *(uint4*)&t[8] = *(const uint4*)(s + 8);
  } else {
    const float* s = (const float*)src + (size_t)(k0 + r) * N + n0 + cseg;
    #pragma unroll
    for (int j = 0; j < 4; j++) {
      float4 v = *(const float4*)(s + j * 4);
      t[j*4+0] = f2b(v.x); t[j*4+1] = f2b(v.y); t[j*4+2] = f2b(v.z); t[j*4+3] = f2b(v.w);
    }
  }
  #pragma unroll
  for (int j = 0; j < 16; j++) Lt[(cseg + j) * 72 + r] = t[j];
  __syncthreads();
  const int n = tid >> 2, kseg = (tid & 3) << 4;
  uint4 u0 = *(const uint4*)&Lt[n * 72 + kseg];
  uint4 u1 = *(const uint4*)&Lt[n * 72 + kseg + 8];
  u16* d = dst + (size_t)(n0 + n) * Kd + k0 + kseg;
  *(uint4*)d = u0;
  *(uint4*)(d + 8) = u1;
}

// ------------------------------------------------- fused prep
// blocks [0,2048): x->bf16 ; [2048,2816): Wqkv^T ; [2816,3072): Wout^T ;
// [3072,3328): RoPE table CS[t*32+f] = {cos,sin}
__global__ __launch_bounds__(256) void prep_kernel(
    const void* __restrict__ x, const void* __restrict__ wqkv,
    const void* __restrict__ wout, const int* __restrict__ flag,
    u16* __restrict__ Xb, u16* __restrict__ Wqkvt, u16* __restrict__ Woutt,
    float2* __restrict__ CS)
{
  __shared__ u16 Lt[64 * 72];
  const int isb = *flag;
  const int bid = blockIdx.x, tid = threadIdx.x;
  if (bid < 2048) {
    const size_t i = ((size_t)bid * 256 + tid) * 8;
    if (isb) {
      *(uint4*)&Xb[i] = *(const uint4*)((const u16*)x + i);
    } else {
      const float* s = (const float*)x + i;
      float4 a = *(const float4*)s, b = *(const float4*)(s + 4);
      uint4 p;
      p.x = pkbf(a.x, a.y); p.y = pkbf(a.z, a.w);
      p.z = pkbf(b.x, b.y); p.w = pkbf(b.z, b.w);
      *(uint4*)&Xb[i] = p;
    }
  } else if (bid < 2816) {
    const int b = bid - 2048;
    tr_tile(wqkv, Wqkvt, 1024, 3072, (b % 48) * 64, (b / 48) * 64, isb, Lt, tid);
  } else if (bid < 3072) {
    const int b = bid - 2816;
    tr_tile(wout, Woutt, 1024, 1024, (b % 16) * 64, (b / 16) * 64, isb, Lt, tid);
  } else {
    const int idx = (bid - 3072) * 256 + tid;   // 65536
    const int t = idx >> 5, f = idx & 31;
    float invf = __expf(-(float)f * 0.2878231366242557f);  // ln(1e4)/32
    float th = (float)t * invf;
    float sn, cs;
    sincosf(th, &sn, &cs);
    CS[idx] = make_float2(cs, sn);
  }
}

// ------------------------------------------------- QKV GEMM (NT, bf16) + RoPE
__global__ __launch_bounds__(256) void qkv_kernel(
    const u16* __restrict__ Xb, const u16* __restrict__ Wt,
    const float2* __restrict__ CS,
    u16* __restrict__ Q, u16* __restrict__ K, u16* __restrict__ Vt)
{
  __shared__ u16 As[128 * 64];
  __shared__ u16 Bs[128 * 64];
  const int tid = threadIdx.x;
  const int n0 = blockIdx.x * 128;
  const int m0 = blockIdx.y * 128;
  const int w = tid >> 6, l = tid & 63, lr = l & 15, lq = l >> 4;
  const int mrow0 = (w & 1) * 64;
  const int ncol0 = (w >> 1) * 64;
  const int srow = tid >> 3;
  const int gseg = (tid & 7) ^ (srow & 7);

  f32x4 acc[4][4] = {};

  for (int k0 = 0; k0 < 1024; k0 += 64) {
    __syncthreads();
    #pragma unroll
    for (int rd = 0; rd < 4; rd++) {
      const int row = srow + rd * 32;
      gl2lds16(Xb + (size_t)(m0 + row) * 1024 + k0 + gseg * 8, &As[tid * 8 + rd * 2048]);
      gl2lds16(Wt + (size_t)(n0 + row) * 1024 + k0 + gseg * 8, &Bs[tid * 8 + rd * 2048]);
    }
    __syncthreads();
    #pragma unroll
    for (int kc = 0; kc < 2; kc++) {
      bf16x8 af[4], bf[4];
      #pragma unroll
      for (int i = 0; i < 4; i++) {
        const int seg = ((kc << 2) | lq) ^ (lr & 7);
        af[i] = *(const bf16x8*)&As[(mrow0 + i * 16 + lr) * 64 + seg * 8];
        bf[i] = *(const bf16x8*)&Bs[(ncol0 + i * 16 + lr) * 64 + seg * 8];
      }
      #pragma unroll
      for (int mb = 0; mb < 4; mb++)
        #pragma unroll
        for (int nb = 0; nb < 4; nb++)
          acc[mb][nb] = __builtin_amdgcn_mfma_f32_16x16x32_bf16(af[mb], bf[nb], acc[mb][nb], 0, 0, 0);
    }
  }

  const int col0 = n0 + ncol0;
  const int sec = col0 >> 10;            // 0=q 1=k 2=v
  const int h = (col0 >> 6) & 15;
  if (sec == 2) {
    #pragma unroll
    for (int mb = 0; mb < 4; mb++) {
      const int row0 = m0 + mrow0 + mb * 16 + lq * 4;
      const int b = row0 >> 11, t0 = row0 & 2047;
      #pragma unroll
      for (int nb = 0; nb < 4; nb++) {
        const int d = nb * 16 + lr;
        uint2 uv;
        uv.x = pkbf(acc[mb][nb][0], acc[mb][nb][1]);
        uv.y = pkbf(acc[mb][nb][2], acc[mb][nb][3]);
        *(uint2*)&Vt[(((size_t)b * 16 + h) * 64 + d) * 2048 + t0] = uv;
      }
    }
  } else {
    u16* dst = (sec == 0) ? Q : K;
    const float qscale = 0.125f * 1.44269504f;   // 1/sqrt(hd) * log2(e), q only
    #pragma unroll
    for (int mb = 0; mb < 4; mb++) {
      const int row0 = m0 + mrow0 + mb * 16 + lq * 4;
      const int b = row0 >> 11, t0 = row0 & 2047;
      #pragma unroll
      for (int nb = 0; nb < 4; nb++) {
        const int d = nb * 16 + lr;
        const int f = d & 31;
        #pragma unroll
        for (int r = 0; r < 4; r++) {
          const int t = t0 + r;
          float2 cs = CS[t * 32 + f];
          float val = acc[mb][nb][r];
          float prt = __shfl_xor(val, 1, 64);   // partner col d^1 = lane lr^1
          float res = fmaf(val, cs.x, ((d & 1) ? prt : -prt) * cs.y);
          if (sec == 0) res *= qscale;
          dst[(((size_t)b * 16 + h) * 2048 + t) * 64 + d] = f2b(res);
        }
      }
    }
  }
}

// ------------------------------------------------- MFMA flash attention (R5)
// Block = 4 waves x 64 q-rows = 256 rows of one (b,h). gridDim.y = ns s-splits.
// S^T = mfma(Kfrag, Qfrag): lane holds 4 consecutive s for fixed m -> pack
// in-lane -> ds_write_b64 into P[m][s] (XOR-swizzled 16B segs, stride 64).
// Double-buffered K/V DMA, one barrier per 64-s tile. LDS exactly 64KB.
__global__ __launch_bounds__(256, 2) void attn_kernel(
    const u16* __restrict__ Q, const u16* __restrict__ K,
    const u16* __restrict__ Vt, u16* __restrict__ ATT,
    float* __restrict__ Op, float* __restrict__ Ls)
{
  __shared__ u16 Ks[2][64 * 64];    // 16 KB
  __shared__ u16 Vs[2][64 * 64];    // 16 KB
  __shared__ u16 Ps[4][64 * 64];    // 32 KB per-wave P, XOR-swizzled
  const int tid = threadIdx.x;
  const int w = tid >> 6, l = tid & 63, lr = l & 15, lq = l >> 4;
  const int bh = blockIdx.x >> 3;
  const int qt = blockIdx.x & 7;
  const int ns = gridDim.y, sh = blockIdx.y;
  const int slen = 2048 / ns;
  const int sbeg = sh * slen;
  const size_t base = (size_t)bh * (2048 * 64);
  const int qrow0 = qt * 256 + w * 64;
  u16* Psw = &Ps[w][0];

  // Q fragments (used as B-operand: col m = lane&15, k = quad*8+j)
  bf16x8 qf[4][2];
  #pragma unroll
  for (int mb = 0; mb < 4; mb++)
    #pragma unroll
    for (int kc = 0; kc < 2; kc++)
      qf[mb][kc] = *(const bf16x8*)(Q + base + (size_t)(qrow0 + mb * 16 + lr) * 64 + kc * 32 + lq * 8);

  f32x4 oa[4][4] = {};            // O^T: [db][mb]
  float lsum[4] = {0.f, 0.f, 0.f, 0.f};

  const int srow = tid >> 3;

  auto stage = [&](int buf, int s0) {
    #pragma unroll
    for (int rd = 0; rd < 2; rd++) {
      const int row = srow + rd * 32;
      const int gs = (tid & 7) ^ (row & 7);
      gl2lds16(K + base + (size_t)(s0 + row) * 64 + gs * 8, &Ks[buf][tid * 8 + rd * 2048]);
      gl2lds16(Vt + base + (size_t)row * 2048 + s0 + gs * 8, &Vs[buf][tid * 8 + rd * 2048]);
    }
  };

  stage(0, sbeg);
  const int nt = slen >> 6;

  #pragma unroll 1
  for (int t = 0; t < nt; t++) {
    const int buf = t & 1;
    __syncthreads();                       // drains DMA for buf, fences prev reads
    if (t + 1 < nt) stage(buf ^ 1, sbeg + (t + 1) * 64);

    bf16x8 kf[4][2], vf[4][2];
    #pragma unroll
    for (int nb = 0; nb < 4; nb++)
      #pragma unroll
      for (int kc = 0; kc < 2; kc++) {
        const int seg = ((kc << 2) | lq) ^ (lr & 7);
        kf[nb][kc] = *(const bf16x8*)&Ks[buf][(nb * 16 + lr) * 64 + seg * 8];
        vf[nb][kc] = *(const bf16x8*)&Vs[buf][(nb * 16 + lr) * 64 + seg * 8];
      }

    // S^T blocks: row s = sb*16+quad*4+r, col m = mb*16+lane&15
    #pragma unroll
    for (int sb = 0; sb < 4; sb++) {
      #pragma unroll
      for (int mb = 0; mb < 4; mb++) {
        f32x4 st = {};
        st = __builtin_amdgcn_mfma_f32_16x16x32_bf16(kf[sb][0], qf[mb][0], st, 0, 0, 0);
        st = __builtin_amdgcn_mfma_f32_16x16x32_bf16(kf[sb][1], qf[mb][1], st, 0, 0, 0);
        float e0 = EXP2F(st[0]), e1 = EXP2F(st[1]), e2 = EXP2F(st[2]), e3 = EXP2F(st[3]);
        lsum[mb] += (e0 + e1) + (e2 + e3);
        uint2 pp;
        pp.x = pkbf(e0, e1);
        pp.y = pkbf(e2, e3);
        // P[m][s]: s = sb*16+lq*4, 16B-seg XOR swizzle: seg=(2sb+lq/2)^(m&7)
        const int pseg = ((sb << 1) | (lq >> 1)) ^ (lr & 7);
        *(uint2*)&Psw[(mb * 16 + lr) * 64 + pseg * 8 + (lq & 1) * 4] = pp;
      }
    }

    // O^T += V^T · P^T : A = Vt-frag (rows d), B = P^T (cols m), k = s
    #pragma unroll
    for (int mb = 0; mb < 4; mb++) {
      const int rs0 = lq ^ (lr & 7);
      const int rs1 = (4 | lq) ^ (lr & 7);
      bf16x8 pf0 = *(const bf16x8*)&Psw[(mb * 16 + lr) * 64 + rs0 * 8];
      bf16x8 pf1 = *(const bf16x8*)&Psw[(mb * 16 + lr) * 64 + rs1 * 8];
      #pragma unroll
      for (int db = 0; db < 4; db++) {
        oa[db][mb] = __builtin_amdgcn_mfma_f32_16x16x32_bf16(vf[db][0], pf0, oa[db][mb], 0, 0, 0);
        oa[db][mb] = __builtin_amdgcn_mfma_f32_16x16x32_bf16(vf[db][1], pf1, oa[db][mb], 0, 0, 0);
      }
    }
  }

  // reduce row sums across quads (lanes lr, lr+16, lr+32, lr+48)
  #pragma unroll
  for (int mb = 0; mb < 4; mb++) {
    float v = lsum[mb];
    v += __shfl_xor(v, 16, 64);
    v += __shfl_xor(v, 32, 64);
    lsum[mb] = v;
  }

  const int b = bh >> 4, h = bh & 15;
  if (ns == 1) {
    #pragma unroll
    for (int mb = 0; mb < 4; mb++) {
      const float inv = 1.f / lsum[mb];
      const int t = qrow0 + mb * 16 + lr;
      u16* dst = ATT + ((size_t)(b * 2048 + t)) * 1024 + h * 64;
      #pragma unroll
      for (int db = 0; db < 4; db++) {
        uint2 u;
        u.x = pkbf(oa[db][mb][0] * inv, oa[db][mb][1] * inv);
        u.y = pkbf(oa[db][mb][2] * inv, oa[db][mb][3] * inv);
        *(uint2*)&dst[db * 16 + lq * 4] = u;
      }
    }
  } else {
    float* op = Op + (size_t)sh * (65536ull * 64);
    #pragma unroll
    for (int mb = 0; mb < 4; mb++) {
      const size_t row = (size_t)bh * 2048 + qrow0 + mb * 16 + lr;
      #pragma unroll
      for (int db = 0; db < 4; db++)
        *(f32x4*)&op[row * 64 + db * 16 + lq * 4] = oa[db][mb];
      if (lq == 0) Ls[(size_t)sh * 65536 + row] = lsum[mb];
    }
  }
}

// ------------------------------------------------- combine s-split partials
__global__ __launch_bounds__(256) void combine_kernel(
    const float* __restrict__ Op, const float* __restrict__ Ls, u16* __restrict__ ATT)
{
  const int idx = blockIdx.x * 256 + threadIdx.x;   // 524288
  const int R = idx >> 3;
  const int c = (idx & 7) * 8;
  const float* p0 = Op + (size_t)R * 64 + c;
  const float* p1 = p0 + 65536ull * 64;
  f32x4 a0 = *(const f32x4*)p0, a1 = *(const f32x4*)(p0 + 4);
  f32x4 b0 = *(const f32x4*)p1, b1 = *(const f32x4*)(p1 + 4);
  const float inv = 1.f / (Ls[R] + Ls[65536 + R]);
  const int bh = R >> 11, trow = R & 2047;
  const int b = bh >> 4, h = bh & 15;
  u16* d = ATT + ((size_t)(b * 2048 + trow)) * 1024 + h * 64 + c;
  uint4 u;
  u.x = pkbf((a0[0] + b0[0]) * inv, (a0[1] + b0[1]) * inv);
  u.y = pkbf((a0[2] + b0[2]) * inv, (a0[3] + b0[3]) * inv);
  u.z = pkbf((a1[0] + b1[0]) * inv, (a1[1] + b1[1]) * inv);
  u.w = pkbf((a1[2] + b1[2]) * inv, (a1[3] + b1[3]) * inv);
  *(uint4*)d = u;
}

// ------------------------------------------------- output projection (NT, bf16)
__global__ __launch_bounds__(256) void outproj_kernel(
    const u16* __restrict__ A, const u16* __restrict__ Wt,
    const int* __restrict__ flag, void* __restrict__ outv)
{
  __shared__ u16 As[128 * 64];
  __shared__ u16 Bs[128 * 64];
  const int isb = *flag;
  const int tid = threadIdx.x;
  const int n0 = blockIdx.x * 128;
  const int m0 = blockIdx.y * 128;
  const int w = tid >> 6, l = tid & 63, lr = l & 15, lq = l >> 4;
  const int mrow0 = (w & 1) * 64;
  const int ncol0 = (w >> 1) * 64;
  const int srow = tid >> 3;
  const int gseg = (tid & 7) ^ (srow & 7);

  f32x4 acc[4][4] = {};

  for (int k0 = 0; k0 < 1024; k0 += 64) {
    __syncthreads();
    #pragma unroll
    for (int rd = 0; rd < 4; rd++) {
      const int row = srow + rd * 32;
      gl2lds16(A + (size_t)(m0 + row) * 1024 + k0 + gseg * 8, &As[tid * 8 + rd * 2048]);
      gl2lds16(Wt + (size_t)(n0 + row) * 1024 + k0 + gseg * 8, &Bs[tid * 8 + rd * 2048]);
    }
    __syncthreads();
    #pragma unroll
    for (int kc = 0; kc < 2; kc++) {
      bf16x8 af[4], bf[4];
      #pragma unroll
      for (int i = 0; i < 4; i++) {
        const int seg = ((kc << 2) | lq) ^ (lr & 7);
        af[i] = *(const bf16x8*)&As[(mrow0 + i * 16 + lr) * 64 + seg * 8];
        bf[i] = *(const bf16x8*)&Bs[(ncol0 + i * 16 + lr) * 64 + seg * 8];
      }
      #pragma unroll
      for (int mb = 0; mb < 4; mb++)
        #pragma unroll
        for (int nb = 0; nb < 4; nb++)
          acc[mb][nb] = __builtin_amdgcn_mfma_f32_16x16x32_bf16(af[mb], bf[nb], acc[mb][nb], 0, 0, 0);
    }
  }
  #pragma unroll
  for (int mb = 0; mb < 4; mb++) {
    const int row = m0 + mrow0 + mb * 16 + lq * 4;
    #pragma unroll
    for (int nb = 0; nb < 4; nb++) {
      const int col = n0 + ncol0 + nb * 16 + lr;
      #pragma unroll
      for (int r = 0; r < 4; r++) {
        float val = acc[mb][nb][r];
        if (isb) ((u16*)outv)[(size_t)(row + r) * 1024 + col] = f2b(val);
        else     ((float*)outv)[(size_t)(row + r) * 1024 + col] = val;
      }
    }
  }
}

extern "C" void kernel_launch(void* const* d_in, const int* in_sizes, int n_in,
                              void* d_out, int out_size, void* d_ws, size_t ws_size,
                              hipStream_t stream)
{
  const void* x    = d_in[0];
  const void* wqkv = d_in[1];
  const void* wout = d_in[2];
  char* ws = (char*)d_ws;
  const size_t MB = 1024 * 1024;
  int*    flag   = (int*)ws;
  float2* CS     = (float2*)(ws + 1024);            // 512 KB
  u16*    Xb     = (u16*)(ws + 1 * MB);             // 8 MB  (aliased by ATT)
  u16*    ATT    = Xb;
  u16*    Wqkvt  = (u16*)(ws + 9 * MB);             // 6 MB
  u16*    Woutt  = (u16*)(ws + 15 * MB);            // 2 MB
  u16*    Q      = (u16*)(ws + 17 * MB);            // 8 MB
  u16*    K      = (u16*)(ws + 25 * MB);            // 8 MB
  u16*    Vt     = (u16*)(ws + 33 * MB);            // 8 MB
  float*  Op     = (float*)(ws + 41 * MB);          // 32 MB (ns=2)
  float*  Ls     = (float*)(ws + 75 * MB);          // 0.5 MB

  const bool split = ws_size >= 76 * MB;            // deterministic across calls
  const int ns = split ? 2 : 1;

  sniff_kernel<<<1, 256, 0, stream>>>((const u16*)x, flag);
  prep_kernel<<<3328, 256, 0, stream>>>(x, wqkv, wout, flag, Xb, Wqkvt, Woutt, CS);
  qkv_kernel<<<dim3(24, 32), 256, 0, stream>>>(Xb, Wqkvt, CS, Q, K, Vt);
  attn_kernel<<<dim3(256, ns), 256, 0, stream>>>(Q, K, Vt, ATT, Op, Ls);
  if (split)
    combine_kernel<<<2048, 256, 0, stream>>>(Op, Ls, ATT);
  outproj_kernel<<<dim3(8, 32), 256, 0, stream>>>(ATT, Woutt, flag, d_out);
}